// Round 1
// 850.599 us; speedup vs baseline: 1.0275x; 1.0275x over previous
//
#include <hip/hip_runtime.h>
#include <stdint.h>

typedef unsigned short u16;
using short8 = __attribute__((ext_vector_type(8))) short;
using f32x4  = __attribute__((ext_vector_type(4))) float;

#define S_LEN 2048
#define NH 32
#define NKV 8
#define HD 128
#define DIM 4096
#define NQ 4096
#define NKVD 1024

typedef __attribute__((address_space(1))) unsigned int uGLB;
typedef __attribute__((address_space(3))) unsigned int uLDS;

__device__ __forceinline__ void g2l16(const u16* g, u16* l) {
  __builtin_amdgcn_global_load_lds((const uGLB*)g, (uLDS*)l, 16, 0, 0);
}

__device__ __forceinline__ float b2f(u16 u) {
  union { unsigned u32; float f; } x; x.u32 = ((unsigned)u) << 16; return x.f;
}
__device__ __forceinline__ u16 f2b(float f) {
  union { float f; unsigned u32; } x; x.f = f;
  unsigned lsb = (x.u32 >> 16) & 1u;
  x.u32 += 0x7fffu + lsb;
  return (u16)(x.u32 >> 16);
}

// ---------------- transpose + cast: in [K][N] fp32 -> out [N][K] bf16 ----------------
__global__ __launch_bounds__(256) void transpose_cast(const float* __restrict__ in,
                                                      u16* __restrict__ out,
                                                      int K, int N) {
  __shared__ float tile[32][33];
  int n0 = blockIdx.x * 32, k0 = blockIdx.y * 32;
  int tx = threadIdx.x, ty = threadIdx.y;
#pragma unroll
  for (int j = 0; j < 4; ++j)
    tile[ty + j * 8][tx] = in[(size_t)(k0 + ty + j * 8) * N + n0 + tx];
  __syncthreads();
#pragma unroll
  for (int j = 0; j < 4; ++j)
    out[(size_t)(n0 + ty + j * 8) * K + k0 + tx] = f2b(tile[tx][ty + j * 8]);
}

__global__ __launch_bounds__(256) void cast_x(const float* __restrict__ in,
                                              u16* __restrict__ out, int n4) {
  int i = blockIdx.x * 256 + threadIdx.x;
  if (i >= n4) return;
  float4 v = reinterpret_cast<const float4*>(in)[i];
  ushort4 u;
  u.x = f2b(v.x); u.y = f2b(v.y); u.z = f2b(v.z); u.w = f2b(v.w);
  reinterpret_cast<ushort4*>(out)[i] = u;
}

// ---------------- 256x256 8-phase GEMM (T1+T2+T3+T4+T5), bt layout ----------------
// A [M][K] bf16, Bt [N][K] bf16, K=4096. 512 threads = 8 waves (2M x 4N).
// LDS: [buf][mat A/B][half][128x64] bf16, st_16x32 swizzle (byte ^= ((byte>>9)&1)<<5)
// applied via pre-swizzled global source (linear global_load_lds dest) + swizzled ds_read.
__global__ __launch_bounds__(512) void gemm256(const u16* __restrict__ A,
                                               const u16* __restrict__ Bt,
                                               int N, int mode,
                                               float* __restrict__ out,
                                               u16* __restrict__ Qb,
                                               u16* __restrict__ Kb,
                                               u16* __restrict__ Vt) {
  const int K = 4096;
  const int NT = 64;  // K / 64
  __shared__ __align__(16) u16 lds[2][2][2][8192];  // 128 KiB

  int tid  = threadIdx.x;
  int lane = tid & 63, w = tid >> 6;
  int ml   = lane & 15, quad = lane >> 4;
  int wm   = w >> 2, wn = w & 3;

  // T1: bijective XCD swizzle (nwg % 8 == 0 at both call sites)
  int nwg = gridDim.x * gridDim.y;
  int bid = blockIdx.y * gridDim.x + blockIdx.x;
  int sbid = (bid & 7) * (nwg >> 3) + (bid >> 3);
  int bx = sbid % gridDim.x, by = sbid / gridDim.x;
  int m0 = by * 256, n0 = bx * 256;

  // staging: per-thread pre-inverse-swizzled source (row,col) within a [128][64] half
  int dst  = w * 1024 + lane * 16;                 // linear LDS byte slot, issue p=0
  int lg   = dst ^ (((lane >> 5) & 1) << 5);       // logical byte = dst ^ bit9->bit5
  int srow = lg >> 7, scol = (lg & 127) >> 1;      // srow in [0,64), p=1 adds 64 rows
  const u16* pA = A  + (size_t)(m0 + srow) * K + scol;
  const u16* pB = Bt + (size_t)(n0 + srow) * K + scol;

  // stage half-tile: dest buffer parity from UNclamped T (last-tile safety);
  // source k-tile clamped to avoid OOB (redundant reload, never consumed).
#define STAGE(mat, T, hh) do { \
    int _b = (T) & 1; \
    int _Tc = (T) < NT ? (T) : (NT - 1); \
    const u16* _s = ((mat) ? pB : pA) + (size_t)(hh) * 128 * K + (size_t)_Tc * 64; \
    u16* _d = &lds[_b][mat][hh][w * 512]; \
    g2l16(_s, _d); \
    g2l16(_s + (size_t)64 * K, _d + 4096); \
  } while (0)

  f32x4 acc[8][4] = {};
  int rxor = ((ml >> 2) & 1) << 5;                 // read-side swizzle (bit9 of logical = row bit2 = ml bit2)
  int aoff = ml * 128 + ((quad * 16) ^ rxor);      // carry-free fields: fold XOR into thread const
  int boff = (wn & 1) * 8192 + aoff;

  // prologue: tile0 complete (A0,A1,B0,B1) + tile1 A0; wait all but last half-tile
  STAGE(0, 0, 0); STAGE(0, 0, 1); STAGE(1, 0, 0); STAGE(1, 0, 1);
  STAGE(0, 1, 0);
  asm volatile("s_waitcnt vmcnt(2)" ::: "memory");
  __builtin_amdgcn_s_barrier();

  short8 af[4][2], bf0[2][2], bf1[2][2];

  for (int t = 0; t < NT; ++t) {
    int buf = t & 1;
    const char* Ab = reinterpret_cast<const char*>(&lds[buf][0][wm][0]);
    const char* Bb = reinterpret_cast<const char*>(&lds[buf][1][wn >> 1][0]);

    // ---- P1: quadrant (mh0, nh0); reads A-half0 (8) + B-nh0 (4) ----
#pragma unroll
    for (int mi = 0; mi < 4; ++mi)
#pragma unroll
      for (int ks = 0; ks < 2; ++ks)
        af[mi][ks] = *reinterpret_cast<const short8*>(Ab + aoff + mi * 2048 + ks * 64);
#pragma unroll
    for (int ni = 0; ni < 2; ++ni)
#pragma unroll
      for (int ks = 0; ks < 2; ++ks)
        bf0[ni][ks] = *reinterpret_cast<const short8*>(Bb + boff + ni * 2048 + ks * 64);
    STAGE(0, t + 1, 1);                           // other buffer: safe
    __builtin_amdgcn_s_barrier();
    asm volatile("s_waitcnt lgkmcnt(0)" ::: "memory");
    __builtin_amdgcn_sched_barrier(0);
    __builtin_amdgcn_s_setprio(1);
#pragma unroll
    for (int mi = 0; mi < 4; ++mi)
#pragma unroll
      for (int ni = 0; ni < 2; ++ni)
#pragma unroll
        for (int ks = 0; ks < 2; ++ks)
          acc[mi][ni] = __builtin_amdgcn_mfma_f32_16x16x32_bf16(af[mi][ks], bf0[ni][ks], acc[mi][ni], 0, 0, 0);
    __builtin_amdgcn_s_setprio(0);
    __builtin_amdgcn_s_barrier();

    // ---- P2: (mh0, nh1); reads B-nh1 (4) ----
#pragma unroll
    for (int ni = 0; ni < 2; ++ni)
#pragma unroll
      for (int ks = 0; ks < 2; ++ks)
        bf1[ni][ks] = *reinterpret_cast<const short8*>(Bb + boff + (2 + ni) * 2048 + ks * 64);
    STAGE(1, t + 1, 0);                           // other buffer: safe
    __builtin_amdgcn_s_barrier();
    asm volatile("s_waitcnt lgkmcnt(0)" ::: "memory");
    __builtin_amdgcn_sched_barrier(0);
    __builtin_amdgcn_s_setprio(1);
#pragma unroll
    for (int mi = 0; mi < 4; ++mi)
#pragma unroll
      for (int ni = 0; ni < 2; ++ni)
#pragma unroll
        for (int ks = 0; ks < 2; ++ks)
          acc[mi][2 + ni] = __builtin_amdgcn_mfma_f32_16x16x32_bf16(af[mi][ks], bf1[ni][ks], acc[mi][2 + ni], 0, 0, 0);
    __builtin_amdgcn_s_setprio(0);
    __builtin_amdgcn_s_barrier();

    // ---- P3: (mh1, nh0); reads A-half1 (8), reuses bf0 regs ----
#pragma unroll
    for (int mi = 0; mi < 4; ++mi)
#pragma unroll
      for (int ks = 0; ks < 2; ++ks)
        af[mi][ks] = *reinterpret_cast<const short8*>(Ab + aoff + 8192 + mi * 2048 + ks * 64);
    STAGE(1, t + 1, 1);                           // other buffer: safe
    __builtin_amdgcn_s_barrier();
    asm volatile("s_waitcnt lgkmcnt(0)" ::: "memory");
    __builtin_amdgcn_sched_barrier(0);
    __builtin_amdgcn_s_setprio(1);
#pragma unroll
    for (int mi = 0; mi < 4; ++mi)
#pragma unroll
      for (int ni = 0; ni < 2; ++ni)
#pragma unroll
        for (int ks = 0; ks < 2; ++ks)
          acc[4 + mi][ni] = __builtin_amdgcn_mfma_f32_16x16x32_bf16(af[mi][ks], bf0[ni][ks], acc[4 + mi][ni], 0, 0, 0);
    __builtin_amdgcn_s_setprio(0);
    __builtin_amdgcn_s_barrier();

    // ---- P4: (mh1, nh1); no ds reads; stage (t+2,A0) into CURRENT buf ----
    // safe: current A region last ds_read completed inside P3 (lgkmcnt(0)),
    // and all waves passed P3's trailing barrier before this issue.
    STAGE(0, t + 2, 0);
    __builtin_amdgcn_s_barrier();
    __builtin_amdgcn_s_setprio(1);
#pragma unroll
    for (int mi = 0; mi < 4; ++mi)
#pragma unroll
      for (int ni = 0; ni < 2; ++ni)
#pragma unroll
        for (int ks = 0; ks < 2; ++ks)
          acc[4 + mi][2 + ni] = __builtin_amdgcn_mfma_f32_16x16x32_bf16(af[mi][ks], bf1[ni][ks], acc[4 + mi][2 + ni], 0, 0, 0);
    __builtin_amdgcn_s_setprio(0);
    // counted drain: all but the freshly issued (t+2,A0) pair => tile t+1 resident
    asm volatile("s_waitcnt vmcnt(2)" ::: "memory");
    __builtin_amdgcn_s_barrier();
  }
#undef STAGE

  // epilogue
#pragma unroll
  for (int mi = 0; mi < 8; ++mi) {
#pragma unroll
    for (int ni = 0; ni < 4; ++ni) {
#pragma unroll
      for (int r = 0; r < 4; ++r) {
        int row = m0 + wm * 128 + mi * 16 + quad * 4 + r;
        int col = n0 + wn * 64 + ni * 16 + ml;
        float v = acc[mi][ni][r];
        if (mode == 1) {
          out[(size_t)row * N + col] = v;
        } else {
          int b = row >> 11, s = row & (S_LEN - 1);
          if (col < NQ) {
            int h = col >> 7, d = col & 127;
            Qb[((size_t)((b * NH + h) * S_LEN + s)) * HD + d] = f2b(v);
          } else if (col < NQ + NKVD) {
            int cc = col - NQ; int h = cc >> 7, d = cc & 127;
            Kb[((size_t)((b * NKV + h) * S_LEN + s)) * HD + d] = f2b(v);
          } else {
            int cc = col - NQ - NKVD; int h = cc >> 7, d = cc & 127;
            Vt[((size_t)((b * NKV + h) * HD + d)) * S_LEN + s] = f2b(v);
          }
        }
      }
    }
  }
}

// ---------------- RoPE in-place ----------------
__global__ __launch_bounds__(256) void rope_ip(u16* __restrict__ X, int npairs) {
  int idx = blockIdx.x * 256 + threadIdx.x;
  if (idx >= npairs) return;
  int i = idx & 63;
  int s = (idx >> 6) & (S_LEN - 1);
  float inv = __expf(-0.2050369278939421f * (float)i);
  float ang = (float)s * inv;
  float sn, cs;
  sincosf(ang, &sn, &cs);
  ushort2 pr = reinterpret_cast<ushort2*>(X)[idx];
  float a = b2f(pr.x), b = b2f(pr.y);
  ushort2 o;
  o.x = f2b(a * cs - b * sn);
  o.y = f2b(a * sn + b * cs);
  reinterpret_cast<ushort2*>(X)[idx] = o;
}

// ---------------- flash attention (S^T orientation, fixed-max, DMA staging) ----------------
__global__ __launch_bounds__(256, 3) void flash(const u16* __restrict__ Qb,
                                                const u16* __restrict__ Kb,
                                                const u16* __restrict__ Vt,
                                                u16* __restrict__ AO) {
  __shared__ __align__(16) u16 Ks[64 * 128];   // [row k][chunk'=chunk^ (row&15)], 16 chunks
  __shared__ __align__(16) u16 Vs[128 * 64];   // [row d][chunk'=chunk^(row&7)], 8 chunks
  __shared__ __align__(16) u16 Ps[4 * 16 * 80];  // per-wave [q=16][k=64 pad->80]

  int tid  = threadIdx.x;
  int lane = tid & 63, w = tid >> 6;
  int ml   = lane & 15, quad = lane >> 4;
  int q_tile = blockIdx.x, h = blockIdx.y, b = blockIdx.z;
  int hkv = h >> 2;
  int q0  = q_tile * 64;
  const u16* Qh = Qb + ((size_t)(b * NH + h) * S_LEN) * HD;
  const u16* Kh = Kb + ((size_t)(b * NKV + hkv) * S_LEN) * HD;
  const u16* Vh = Vt + ((size_t)(b * NKV + hkv) * HD) * S_LEN;
  u16* Pw = Ps + w * 16 * 80;

  // hoist Q B-fragments (lane = q row, quad packs k)
  short8 qf[4];
#pragma unroll
  for (int ks = 0; ks < 4; ++ks)
    qf[ks] = *reinterpret_cast<const short8*>(
        Qh + (size_t)(q0 + w * 16 + ml) * HD + ks * 32 + quad * 8);

  short8 ones8;
  {
    u16 one_b = 0x3f80;
#pragma unroll
    for (int j = 0; j < 8; ++j) ones8[j] = (short)one_b;
  }

  f32x4 o[8] = {};
  f32x4 o9 = {};
  const float SC = 0.12751745f;  // (1/sqrt(128)) * log2(e)
  const float BIAS = 18.0f;

  int qg = q0 + w * 16 + ml;
  int ntile = q_tile + 1;
  for (int it = 0; it < ntile; ++it) {
    int kv0 = it * 64;
    __syncthreads();
    // stage K tile (64 x 128) and V tile (128 x 64) via DMA, swizzled
#pragma unroll
    for (int p = 0; p < 4; ++p) {
      int slot = w * 256 + p * 64 + lane;
      int krow = slot >> 4, kch = slot & 15;
      int ksrc = kch ^ (krow & 15);
      g2l16(Kh + (size_t)(kv0 + krow) * HD + ksrc * 8, &Ks[(w * 256 + p * 64) * 8]);
      int vrow = slot >> 3, vch = slot & 7;
      int vsrc = vch ^ (vrow & 7);
      g2l16(Vh + (size_t)vrow * S_LEN + kv0 + vsrc * 8, &Vs[(w * 256 + p * 64) * 8]);
    }
    __syncthreads();

    // S^T tiles: mfma(A=K rows, B=Q rows) -> C[k][q], col=q=ml, row=k=quad*4+r
    f32x4 st[4] = {};
#pragma unroll
    for (int ks = 0; ks < 4; ++ks) {
#pragma unroll
      for (int nt = 0; nt < 4; ++nt) {
        int row = nt * 16 + ml;
        int ch = ((ks << 2) | quad) ^ ml;
        short8 kf = *reinterpret_cast<const short8*>(&Ks[row * 128 + ch * 8]);
        st[nt] = __builtin_amdgcn_mfma_f32_16x16x32_bf16(kf, qf[ks], st[nt], 0, 0, 0);
      }
    }

    bool diag = (it == q_tile);
#pragma unroll
    for (int nt = 0; nt < 4; ++nt) {
      float p0 = exp2f(fmaf(st[nt][0], SC, -BIAS));
      float p1 = exp2f(fmaf(st[nt][1], SC, -BIAS));
      float p2 = exp2f(fmaf(st[nt][2], SC, -BIAS));
      float p3 = exp2f(fmaf(st[nt][3], SC, -BIAS));
      if (diag) {
        int kg = kv0 + nt * 16 + quad * 4;
        if (kg + 0 > qg) p0 = 0.f;
        if (kg + 1 > qg) p1 = 0.f;
        if (kg + 2 > qg) p2 = 0.f;
        if (kg + 3 > qg) p3 = 0.f;
      }
      uint2 pk;
      pk.x = (unsigned)f2b(p0) | ((unsigned)f2b(p1) << 16);
      pk.y = (unsigned)f2b(p2) | ((unsigned)f2b(p3) << 16);
      *reinterpret_cast<uint2*>(&Pw[ml * 80 + nt * 16 + quad * 4]) = pk;
    }
    // wave-private Ps: no barrier needed (lgkmcnt wait auto-inserted)

#pragma unroll
    for (int ks2 = 0; ks2 < 2; ++ks2) {
      short8 pf = *reinterpret_cast<const short8*>(&Pw[ml * 80 + ks2 * 32 + quad * 8]);
#pragma unroll
      for (int dt = 0; dt < 8; ++dt) {
        int row = dt * 16 + ml;
        int ch = ((ks2 << 2) | quad) ^ (ml & 7);
        short8 vf = *reinterpret_cast<const short8*>(&Vs[row * 64 + ch * 8]);
        o[dt] = __builtin_amdgcn_mfma_f32_16x16x32_bf16(pf, vf, o[dt], 0, 0, 0);
      }
      o9 = __builtin_amdgcn_mfma_f32_16x16x32_bf16(pf, ones8, o9, 0, 0, 0);
    }
  }

  size_t row_base = (size_t)(b * S_LEN + q0 + w * 16 + quad * 4);
#pragma unroll
  for (int r = 0; r < 4; ++r) {
    float inv_l = 1.0f / o9[r];
#pragma unroll
    for (int dt = 0; dt < 8; ++dt) {
      int col = h * HD + dt * 16 + ml;
      AO[(row_base + r) * (size_t)DIM + col] = f2b(o[dt][r] * inv_l);
    }
  }
}

extern "C" void kernel_launch(void* const* d_in, const int* in_sizes, int n_in,
                              void* d_out, int out_size, void* d_ws, size_t ws_size,
                              hipStream_t stream) {
  const float* x  = (const float*)d_in[0];
  const float* wq = (const float*)d_in[1];
  const float* wk = (const float*)d_in[2];
  const float* wv = (const float*)d_in[3];
  const float* wo = (const float*)d_in[4];
  float* out = (float*)d_out;
  char* ws = (char*)d_ws;

  u16* Wqt = (u16*)(ws + 0);          // [4096][4096], later wo^T
  u16* Wkt = (u16*)(ws + 33554432);   // [1024][4096]
  u16* Wvt = (u16*)(ws + 41943040);   // [1024][4096]
  u16* Xb  = (u16*)(ws + 50331648);   // [4096][4096], later AO
  u16* Qb  = (u16*)(ws + 83886080);
  u16* Kb  = (u16*)(ws + 117440512);
  u16* Vt  = (u16*)(ws + 125829120);

  transpose_cast<<<dim3(128, 128), dim3(32, 8), 0, stream>>>(wq, Wqt, 4096, 4096);
  transpose_cast<<<dim3(32, 128),  dim3(32, 8), 0, stream>>>(wk, Wkt, 4096, 1024);
  transpose_cast<<<dim3(32, 128),  dim3(32, 8), 0, stream>>>(wv, Wvt, 4096, 1024);
  cast_x<<<16384, 256, 0, stream>>>(x, Xb, 4194304);

  // QKV projection: M=4096, N=6144, K=4096 (Wq|Wk|Wv transposed contiguously)
  gemm256<<<dim3(24, 16), 512, 0, stream>>>(Xb, Wqt, 6144, 0, nullptr, Qb, Kb, Vt);

  rope_ip<<<32768, 256, 0, stream>>>(Qb, 8388608);
  rope_ip<<<8192, 256, 0, stream>>>(Kb, 2097152);

  transpose_cast<<<dim3(128, 128), dim3(32, 8), 0, stream>>>(wo, Wqt, 4096, 4096);

  flash<<<dim3(32, 32, 2), 256, 0, stream>>>(Qb, Kb, Vt, Xb);

  // output projection: M=4096, N=4096, K=4096
  gemm256<<<dim3(16, 16), 512, 0, stream>>>(Xb, Wqt, 4096, 1, out, nullptr, nullptr, nullptr);
}

// Round 3
// 823.006 us; speedup vs baseline: 1.0619x; 1.0335x over previous
//
#include <hip/hip_runtime.h>
#include <stdint.h>

typedef unsigned short u16;
using short8 = __attribute__((ext_vector_type(8))) short;
using f32x4  = __attribute__((ext_vector_type(4))) float;

#define S_LEN 2048
#define NH 32
#define NKV 8
#define HD 128
#define DIM 4096
#define NQ 4096
#define NKVD 1024

typedef __attribute__((address_space(1))) unsigned int uGLB;
typedef __attribute__((address_space(3))) unsigned int uLDS;

__device__ __forceinline__ void g2l16(const u16* g, u16* l) {
  __builtin_amdgcn_global_load_lds((const uGLB*)g, (uLDS*)l, 16, 0, 0);
}

__device__ __forceinline__ float b2f(u16 u) {
  union { unsigned u32; float f; } x; x.u32 = ((unsigned)u) << 16; return x.f;
}
__device__ __forceinline__ u16 f2b(float f) {
  union { float f; unsigned u32; } x; x.f = f;
  unsigned lsb = (x.u32 >> 16) & 1u;
  x.u32 += 0x7fffu + lsb;
  return (u16)(x.u32 >> 16);
}

// ---------------- transpose + cast: in [K][N] fp32 -> out [N][K] bf16 ----------------
__global__ __launch_bounds__(256) void transpose_cast(const float* __restrict__ in,
                                                      u16* __restrict__ out,
                                                      int K, int N) {
  __shared__ float tile[32][33];
  int n0 = blockIdx.x * 32, k0 = blockIdx.y * 32;
  int tx = threadIdx.x, ty = threadIdx.y;
#pragma unroll
  for (int j = 0; j < 4; ++j)
    tile[ty + j * 8][tx] = in[(size_t)(k0 + ty + j * 8) * N + n0 + tx];
  __syncthreads();
#pragma unroll
  for (int j = 0; j < 4; ++j)
    out[(size_t)(n0 + ty + j * 8) * K + k0 + tx] = f2b(tile[tx][ty + j * 8]);
}

__global__ __launch_bounds__(256) void cast_x(const float* __restrict__ in,
                                              u16* __restrict__ out, int n4) {
  int i = blockIdx.x * 256 + threadIdx.x;
  if (i >= n4) return;
  float4 v = reinterpret_cast<const float4*>(in)[i];
  ushort4 u;
  u.x = f2b(v.x); u.y = f2b(v.y); u.z = f2b(v.z); u.w = f2b(v.w);
  reinterpret_cast<ushort4*>(out)[i] = u;
}

// ---------------- 256x256 4-phase GEMM (out-projection), ch^(row&7) swizzle ----------------
// A [M][K] bf16, Bt [N][K] bf16, K=4096. 512 threads = 8 waves (2M x 4N).
// LDS halves [128 rows][64 cols] bf16 (128B rows, 8 chunks of 16B);
// physical chunk = logical chunk ^ (row & 7): conflict-free ds_read_b128,
// applied via pre-swizzled global source (linear global_load_lds dest) + swizzled read addr.
__global__ __launch_bounds__(512) void gemm256(const u16* __restrict__ A,
                                               const u16* __restrict__ Bt,
                                               int N,
                                               float* __restrict__ out) {
  const int K = 4096;
  const int NT = 64;  // K / 64
  __shared__ __align__(16) u16 lds[2][2][2][8192];  // 128 KiB

  int tid  = threadIdx.x;
  int lane = tid & 63, w = tid >> 6;
  int ml   = lane & 15, quad = lane >> 4;
  int wm   = w >> 2, wn = w & 3;

  // T1: bijective XCD swizzle (nwg % 8 == 0)
  int nwg = gridDim.x * gridDim.y;
  int bid = blockIdx.y * gridDim.x + blockIdx.x;
  int sbid = (bid & 7) * (nwg >> 3) + (bid >> 3);
  int bx = sbid % gridDim.x, by = sbid / gridDim.x;
  int m0 = by * 256, n0 = bx * 256;

  // staging: physical LDS slot (row r, chunk cp) holds global chunk cg = cp ^ (r&7)
  int dstB = w * 1024 + lane * 16;                 // linear LDS byte slot (8KB segment)
  int r    = dstB >> 7;                            // row 0..63 (second load: +64, (r+64)&7==r&7)
  int cg   = ((dstB >> 4) & 7) ^ (r & 7);
  const u16* pA = A  + (size_t)(m0 + r) * K + cg * 8;
  const u16* pB = Bt + (size_t)(n0 + r) * K + cg * 8;

#define STAGE(mat, T, hh) do { \
    int _b = (T) & 1; \
    int _Tc = (T) < NT ? (T) : (NT - 1); \
    const u16* _s = ((mat) ? pB : pA) + (size_t)(hh) * 128 * K + (size_t)_Tc * 64; \
    u16* _d = &lds[_b][mat][hh][w * 512]; \
    g2l16(_s, _d); \
    g2l16(_s + (size_t)64 * K, _d + 4096); \
  } while (0)

  f32x4 acc[8][4] = {};
  int cxa  = (quad ^ (ml & 7)) << 4;               // chunk byte for ks=0; ks flips bit6
  int aoff = ml * 128 + cxa;
  int boff = (wn & 1) * 8192 + aoff;

  STAGE(0, 0, 0); STAGE(0, 0, 1); STAGE(1, 0, 0); STAGE(1, 0, 1);
  STAGE(0, 1, 0);
  asm volatile("s_waitcnt vmcnt(2)" ::: "memory");
  __builtin_amdgcn_s_barrier();

  short8 af[4][2], bf0[2][2], bf1[2][2];

  for (int t = 0; t < NT; ++t) {
    int buf = t & 1;
    const char* Ab = reinterpret_cast<const char*>(&lds[buf][0][wm][0]);
    const char* Bb = reinterpret_cast<const char*>(&lds[buf][1][wn >> 1][0]);

    // ---- P1: quadrant (mh0, nh0) ----
#pragma unroll
    for (int mi = 0; mi < 4; ++mi)
#pragma unroll
      for (int ks = 0; ks < 2; ++ks)
        af[mi][ks] = *reinterpret_cast<const short8*>(Ab + (aoff ^ (ks << 6)) + mi * 2048);
#pragma unroll
    for (int ni = 0; ni < 2; ++ni)
#pragma unroll
      for (int ks = 0; ks < 2; ++ks)
        bf0[ni][ks] = *reinterpret_cast<const short8*>(Bb + (boff ^ (ks << 6)) + ni * 2048);
    STAGE(0, t + 1, 1);
    __builtin_amdgcn_s_barrier();
    asm volatile("s_waitcnt lgkmcnt(0)" ::: "memory");
    __builtin_amdgcn_sched_barrier(0);
    __builtin_amdgcn_s_setprio(1);
#pragma unroll
    for (int mi = 0; mi < 4; ++mi)
#pragma unroll
      for (int ni = 0; ni < 2; ++ni)
#pragma unroll
        for (int ks = 0; ks < 2; ++ks)
          acc[mi][ni] = __builtin_amdgcn_mfma_f32_16x16x32_bf16(af[mi][ks], bf0[ni][ks], acc[mi][ni], 0, 0, 0);
    __builtin_amdgcn_s_setprio(0);
    __builtin_amdgcn_s_barrier();

    // ---- P2: (mh0, nh1) ----
#pragma unroll
    for (int ni = 0; ni < 2; ++ni)
#pragma unroll
      for (int ks = 0; ks < 2; ++ks)
        bf1[ni][ks] = *reinterpret_cast<const short8*>(Bb + (boff ^ (ks << 6)) + (2 + ni) * 2048);
    STAGE(1, t + 1, 0);
    __builtin_amdgcn_s_barrier();
    asm volatile("s_waitcnt lgkmcnt(0)" ::: "memory");
    __builtin_amdgcn_sched_barrier(0);
    __builtin_amdgcn_s_setprio(1);
#pragma unroll
    for (int mi = 0; mi < 4; ++mi)
#pragma unroll
      for (int ni = 0; ni < 2; ++ni)
#pragma unroll
        for (int ks = 0; ks < 2; ++ks)
          acc[mi][2 + ni] = __builtin_amdgcn_mfma_f32_16x16x32_bf16(af[mi][ks], bf1[ni][ks], acc[mi][2 + ni], 0, 0, 0);
    __builtin_amdgcn_s_setprio(0);
    __builtin_amdgcn_s_barrier();

    // ---- P3: (mh1, nh0) ----
#pragma unroll
    for (int mi = 0; mi < 4; ++mi)
#pragma unroll
      for (int ks = 0; ks < 2; ++ks)
        af[mi][ks] = *reinterpret_cast<const short8*>(Ab + 8192 + (aoff ^ (ks << 6)) + mi * 2048);
    STAGE(1, t + 1, 1);
    __builtin_amdgcn_s_barrier();
    asm volatile("s_waitcnt lgkmcnt(0)" ::: "memory");
    __builtin_amdgcn_sched_barrier(0);
    __builtin_amdgcn_s_setprio(1);
#pragma unroll
    for (int mi = 0; mi < 4; ++mi)
#pragma unroll
      for (int ni = 0; ni < 2; ++ni)
#pragma unroll
        for (int ks = 0; ks < 2; ++ks)
          acc[4 + mi][ni] = __builtin_amdgcn_mfma_f32_16x16x32_bf16(af[mi][ks], bf0[ni][ks], acc[4 + mi][ni], 0, 0, 0);
    __builtin_amdgcn_s_setprio(0);
    __builtin_amdgcn_s_barrier();

    // ---- P4: (mh1, nh1); stage (t+2,A0) into CURRENT buf (A reads done in P3) ----
    STAGE(0, t + 2, 0);
    __builtin_amdgcn_s_barrier();
    __builtin_amdgcn_s_setprio(1);
#pragma unroll
    for (int mi = 0; mi < 4; ++mi)
#pragma unroll
      for (int ni = 0; ni < 2; ++ni)
#pragma unroll
        for (int ks = 0; ks < 2; ++ks)
          acc[4 + mi][2 + ni] = __builtin_amdgcn_mfma_f32_16x16x32_bf16(af[mi][ks], bf1[ni][ks], acc[4 + mi][2 + ni], 0, 0, 0);
    __builtin_amdgcn_s_setprio(0);
    asm volatile("s_waitcnt vmcnt(2)" ::: "memory");
    __builtin_amdgcn_s_barrier();
  }
#undef STAGE

#pragma unroll
  for (int mi = 0; mi < 8; ++mi) {
#pragma unroll
    for (int ni = 0; ni < 4; ++ni) {
#pragma unroll
      for (int rr = 0; rr < 4; ++rr) {
        int row = m0 + wm * 128 + mi * 16 + quad * 4 + rr;
        int col = n0 + wn * 64 + ni * 16 + ml;
        out[(size_t)row * N + col] = acc[mi][ni][rr];
      }
    }
  }
}

// ---------------- 128x256 2-phase GEMM (QKV projection + scatter) ----------------
// grid (24, 32) = 768 blocks = 3 exact rounds of 256 CUs. 96 KiB LDS, 8 waves (2M x 4N),
// wave tile 64x64, 16 MFMA per phase. Same ch^(row&7) swizzle as gemm256.
// Leads: A(t+1) staged in P1 (other buf); B(t+2) staged in P2 into CURRENT buf
// (safe: all B reads issue in P1 and drain at P1's lgkmcnt(0) before its barrier).
__global__ __launch_bounds__(512) void gemm128(const u16* __restrict__ A,
                                               const u16* __restrict__ Bt,
                                               u16* __restrict__ Qb,
                                               u16* __restrict__ Kb,
                                               u16* __restrict__ Vt) {
  const int K = 4096;
  const int NT = 64;
  // LDS byte map: A(b,h) = b*16384 + h*8192 (2x2x[64][64] = 32KB)
  //               B(b,h) = 32768 + b*32768 + h*16384 (2x2x[128][64] = 64KB)
  __shared__ __align__(16) char L[98304];

  int tid  = threadIdx.x;
  int lane = tid & 63, w = tid >> 6;
  int ml   = lane & 15, quad = lane >> 4;
  int wm   = w >> 2, wn = w & 3;

  int nwg = gridDim.x * gridDim.y;   // 768, % 8 == 0
  int bid = blockIdx.y * gridDim.x + blockIdx.x;
  int sbid = (bid & 7) * (nwg >> 3) + (bid >> 3);
  int bx = sbid % gridDim.x, by = sbid / gridDim.x;
  int m0 = by * 128, n0 = bx * 256;

  int dstB = w * 1024 + lane * 16;
  int r    = dstB >> 7;              // 0..63
  int cg   = ((dstB >> 4) & 7) ^ (r & 7);
  const u16* pA = A  + (size_t)(m0 + r) * K + cg * 8;
  const u16* pB = Bt + (size_t)(n0 + r) * K + cg * 8;

#define STAGE_A(T, h) do { \
    int _b = (T) & 1; int _Tc = (T) < NT ? (T) : (NT - 1); \
    g2l16(pA + (size_t)(h) * 64 * K + (size_t)_Tc * 64, \
          (u16*)(L + _b * 16384 + (h) * 8192 + w * 1024)); \
  } while (0)
#define STAGE_B(T, h) do { \
    int _b = (T) & 1; int _Tc = (T) < NT ? (T) : (NT - 1); \
    const u16* _s = pB + (size_t)(h) * 128 * K + (size_t)_Tc * 64; \
    char* _d = L + 32768 + _b * 32768 + (h) * 16384 + w * 1024; \
    g2l16(_s, (u16*)_d); \
    g2l16(_s + (size_t)64 * K, (u16*)(_d + 8192)); \
  } while (0)

  f32x4 acc[4][4] = {};
  int cxa  = (quad ^ (ml & 7)) << 4;
  int aoff = ml * 128 + cxa;
  int boff = (wn & 1) * 8192 + aoff;

  // prologue: tile0 (6 loads) + B(1) (4 loads, long lead); drain tile0
  STAGE_A(0, 0); STAGE_A(0, 1); STAGE_B(0, 0); STAGE_B(0, 1);
  STAGE_B(1, 0); STAGE_B(1, 1);
  asm volatile("s_waitcnt vmcnt(4)" ::: "memory");
  __builtin_amdgcn_s_barrier();

  short8 af[2][2], af2[2][2], bf[4][2];

  for (int t = 0; t < NT; ++t) {
    int buf = t & 1;
    const char* Ab = L + buf * 16384 + wm * 8192;
    const char* Bb = L + 32768 + buf * 32768 + (wn >> 1) * 16384;

    // ---- P1: wave rows 0..31, all 64 n-cols; reads af(4) + bf(8) ----
#pragma unroll
    for (int mi = 0; mi < 2; ++mi)
#pragma unroll
      for (int ks = 0; ks < 2; ++ks)
        af[mi][ks] = *reinterpret_cast<const short8*>(Ab + (aoff ^ (ks << 6)) + mi * 2048);
#pragma unroll
    for (int ni = 0; ni < 4; ++ni)
#pragma unroll
      for (int ks = 0; ks < 2; ++ks)
        bf[ni][ks] = *reinterpret_cast<const short8*>(Bb + (boff ^ (ks << 6)) + ni * 2048);
    STAGE_A(t + 1, 0); STAGE_A(t + 1, 1);   // other buffer
    __builtin_amdgcn_s_barrier();
    asm volatile("s_waitcnt lgkmcnt(0)" ::: "memory");
    __builtin_amdgcn_sched_barrier(0);
    __builtin_amdgcn_s_setprio(1);
#pragma unroll
    for (int mi = 0; mi < 2; ++mi)
#pragma unroll
      for (int ni = 0; ni < 4; ++ni)
#pragma unroll
        for (int ks = 0; ks < 2; ++ks)
          acc[mi][ni] = __builtin_amdgcn_mfma_f32_16x16x32_bf16(af[mi][ks], bf[ni][ks], acc[mi][ni], 0, 0, 0);
    __builtin_amdgcn_s_setprio(0);
    __builtin_amdgcn_s_barrier();

    // ---- P2: wave rows 32..63; reads af2(4); stage B(t+2) into CURRENT buf ----
#pragma unroll
    for (int mi = 0; mi < 2; ++mi)
#pragma unroll
      for (int ks = 0; ks < 2; ++ks)
        af2[mi][ks] = *reinterpret_cast<const short8*>(Ab + 4096 + (aoff ^ (ks << 6)) + mi * 2048);
    STAGE_B(t + 2, 0); STAGE_B(t + 2, 1);
    __builtin_amdgcn_s_barrier();
    asm volatile("s_waitcnt lgkmcnt(0)" ::: "memory");
    __builtin_amdgcn_sched_barrier(0);
    __builtin_amdgcn_s_setprio(1);
#pragma unroll
    for (int mi = 0; mi < 2; ++mi)
#pragma unroll
      for (int ni = 0; ni < 4; ++ni)
#pragma unroll
        for (int ks = 0; ks < 2; ++ks)
          acc[2 + mi][ni] = __builtin_amdgcn_mfma_f32_16x16x32_bf16(af2[mi][ks], bf[ni][ks], acc[2 + mi][ni], 0, 0, 0);
    __builtin_amdgcn_s_setprio(0);
    // counted drain: leave only B(t+2)'s 4 loads in flight -> tile t+1 resident
    asm volatile("s_waitcnt vmcnt(4)" ::: "memory");
    __builtin_amdgcn_s_barrier();
  }
#undef STAGE_A
#undef STAGE_B

  // epilogue: scatter to Qb/Kb/Vt (bf16)
#pragma unroll
  for (int a = 0; a < 4; ++a) {
#pragma unroll
    for (int ni = 0; ni < 4; ++ni) {
#pragma unroll
      for (int rr = 0; rr < 4; ++rr) {
        int row = m0 + wm * 64 + a * 16 + quad * 4 + rr;
        int col = n0 + wn * 64 + ni * 16 + ml;
        float v = acc[a][ni][rr];
        int b = row >> 11, s = row & (S_LEN - 1);
        if (col < NQ) {
          int h = col >> 7, d = col & 127;
          Qb[((size_t)((b * NH + h) * S_LEN + s)) * HD + d] = f2b(v);
        } else if (col < NQ + NKVD) {
          int cc = col - NQ; int h = cc >> 7, d = cc & 127;
          Kb[((size_t)((b * NKV + h) * S_LEN + s)) * HD + d] = f2b(v);
        } else {
          int cc = col - NQ - NKVD; int h = cc >> 7, d = cc & 127;
          Vt[((size_t)((b * NKV + h) * HD + d)) * S_LEN + s] = f2b(v);
        }
      }
    }
  }
}

// ---------------- RoPE in-place ----------------
__global__ __launch_bounds__(256) void rope_ip(u16* __restrict__ X, int npairs) {
  int idx = blockIdx.x * 256 + threadIdx.x;
  if (idx >= npairs) return;
  int i = idx & 63;
  int s = (idx >> 6) & (S_LEN - 1);
  float inv = __expf(-0.2050369278939421f * (float)i);
  float ang = (float)s * inv;
  float sn, cs;
  sincosf(ang, &sn, &cs);
  ushort2 pr = reinterpret_cast<ushort2*>(X)[idx];
  float a = b2f(pr.x), b = b2f(pr.y);
  ushort2 o;
  o.x = f2b(a * cs - b * sn);
  o.y = f2b(a * sn + b * cs);
  reinterpret_cast<ushort2*>(X)[idx] = o;
}

// ---------------- flash attention (S^T orientation, fixed-max, DMA staging) ----------------
__global__ __launch_bounds__(256, 3) void flash(const u16* __restrict__ Qb,
                                                const u16* __restrict__ Kb,
                                                const u16* __restrict__ Vt,
                                                u16* __restrict__ AO) {
  __shared__ __align__(16) u16 Ks[64 * 128];   // [row k][chunk'=chunk^ (row&15)], 16 chunks
  __shared__ __align__(16) u16 Vs[128 * 64];   // [row d][chunk'=chunk^(row&7)], 8 chunks
  __shared__ __align__(16) u16 Ps[4 * 16 * 80];  // per-wave [q=16][k=64 pad->80]

  int tid  = threadIdx.x;
  int lane = tid & 63, w = tid >> 6;
  int ml   = lane & 15, quad = lane >> 4;
  int q_tile = blockIdx.x, h = blockIdx.y, b = blockIdx.z;
  int hkv = h >> 2;
  int q0  = q_tile * 64;
  const u16* Qh = Qb + ((size_t)(b * NH + h) * S_LEN) * HD;
  const u16* Kh = Kb + ((size_t)(b * NKV + hkv) * S_LEN) * HD;
  const u16* Vh = Vt + ((size_t)(b * NKV + hkv) * HD) * S_LEN;
  u16* Pw = Ps + w * 16 * 80;

  // hoist Q B-fragments (lane = q row, quad packs k)
  short8 qf[4];
#pragma unroll
  for (int ks = 0; ks < 4; ++ks)
    qf[ks] = *reinterpret_cast<const short8*>(
        Qh + (size_t)(q0 + w * 16 + ml) * HD + ks * 32 + quad * 8);

  short8 ones8;
  {
    u16 one_b = 0x3f80;
#pragma unroll
    for (int j = 0; j < 8; ++j) ones8[j] = (short)one_b;
  }

  f32x4 o[8] = {};
  f32x4 o9 = {};
  const float SC = 0.12751745f;  // (1/sqrt(128)) * log2(e)
  const float BIAS = 18.0f;

  int qg = q0 + w * 16 + ml;
  int ntile = q_tile + 1;
  for (int it = 0; it < ntile; ++it) {
    int kv0 = it * 64;
    __syncthreads();
    // stage K tile (64 x 128) and V tile (128 x 64) via DMA, swizzled
#pragma unroll
    for (int p = 0; p < 4; ++p) {
      int slot = w * 256 + p * 64 + lane;
      int krow = slot >> 4, kch = slot & 15;
      int ksrc = kch ^ (krow & 15);
      g2l16(Kh + (size_t)(kv0 + krow) * HD + ksrc * 8, &Ks[(w * 256 + p * 64) * 8]);
      int vrow = slot >> 3, vch = slot & 7;
      int vsrc = vch ^ (vrow & 7);
      g2l16(Vh + (size_t)vrow * S_LEN + kv0 + vsrc * 8, &Vs[(w * 256 + p * 64) * 8]);
    }
    __syncthreads();

    // S^T tiles: mfma(A=K rows, B=Q rows) -> C[k][q], col=q=ml, row=k=quad*4+r
    f32x4 st[4] = {};
#pragma unroll
    for (int ks = 0; ks < 4; ++ks) {
#pragma unroll
      for (int nt = 0; nt < 4; ++nt) {
        int row = nt * 16 + ml;
        int ch = ((ks << 2) | quad) ^ ml;
        short8 kf = *reinterpret_cast<const short8*>(&Ks[row * 128 + ch * 8]);
        st[nt] = __builtin_amdgcn_mfma_f32_16x16x32_bf16(kf, qf[ks], st[nt], 0, 0, 0);
      }
    }

    bool diag = (it == q_tile);
#pragma unroll
    for (int nt = 0; nt < 4; ++nt) {
      float p0 = exp2f(fmaf(st[nt][0], SC, -BIAS));
      float p1 = exp2f(fmaf(st[nt][1], SC, -BIAS));
      float p2 = exp2f(fmaf(st[nt][2], SC, -BIAS));
      float p3 = exp2f(fmaf(st[nt][3], SC, -BIAS));
      if (diag) {
        int kg = kv0 + nt * 16 + quad * 4;
        if (kg + 0 > qg) p0 = 0.f;
        if (kg + 1 > qg) p1 = 0.f;
        if (kg + 2 > qg) p2 = 0.f;
        if (kg + 3 > qg) p3 = 0.f;
      }
      uint2 pk;
      pk.x = (unsigned)f2b(p0) | ((unsigned)f2b(p1) << 16);
      pk.y = (unsigned)f2b(p2) | ((unsigned)f2b(p3) << 16);
      *reinterpret_cast<uint2*>(&Pw[ml * 80 + nt * 16 + quad * 4]) = pk;
    }
    // wave-private Ps: no barrier needed (lgkmcnt wait auto-inserted)

#pragma unroll
    for (int ks2 = 0; ks2 < 2; ++ks2) {
      short8 pf = *reinterpret_cast<const short8*>(&Pw[ml * 80 + ks2 * 32 + quad * 8]);
#pragma unroll
      for (int dt = 0; dt < 8; ++dt) {
        int row = dt * 16 + ml;
        int ch = ((ks2 << 2) | quad) ^ (ml & 7);
        short8 vf = *reinterpret_cast<const short8*>(&Vs[row * 64 + ch * 8]);
        o[dt] = __builtin_amdgcn_mfma_f32_16x16x32_bf16(pf, vf, o[dt], 0, 0, 0);
      }
      o9 = __builtin_amdgcn_mfma_f32_16x16x32_bf16(pf, ones8, o9, 0, 0, 0);
    }
  }

  size_t row_base = (size_t)(b * S_LEN + q0 + w * 16 + quad * 4);
#pragma unroll
  for (int rr = 0; rr < 4; ++rr) {
    float inv_l = 1.0f / o9[rr];
#pragma unroll
    for (int dt = 0; dt < 8; ++dt) {
      int col = h * HD + dt * 16 + ml;
      AO[(row_base + rr) * (size_t)DIM + col] = f2b(o[dt][rr] * inv_l);
    }
  }
}

extern "C" void kernel_launch(void* const* d_in, const int* in_sizes, int n_in,
                              void* d_out, int out_size, void* d_ws, size_t ws_size,
                              hipStream_t stream) {
  const float* x  = (const float*)d_in[0];
  const float* wq = (const float*)d_in[1];
  const float* wk = (const float*)d_in[2];
  const float* wv = (const float*)d_in[3];
  const float* wo = (const float*)d_in[4];
  float* out = (float*)d_out;
  char* ws = (char*)d_ws;

  u16* Wqt = (u16*)(ws + 0);          // [4096][4096], later wo^T
  u16* Wkt = (u16*)(ws + 33554432);   // [1024][4096]
  u16* Wvt = (u16*)(ws + 41943040);   // [1024][4096]
  u16* Xb  = (u16*)(ws + 50331648);   // [4096][4096] bf16, later AO
  u16* Qb  = (u16*)(ws + 83886080);
  u16* Kb  = (u16*)(ws + 117440512);
  u16* Vt  = (u16*)(ws + 125829120);

  transpose_cast<<<dim3(128, 128), dim3(32, 8), 0, stream>>>(wq, Wqt, 4096, 4096);
  transpose_cast<<<dim3(32, 128),  dim3(32, 8), 0, stream>>>(wk, Wkt, 4096, 1024);
  transpose_cast<<<dim3(32, 128),  dim3(32, 8), 0, stream>>>(wv, Wvt, 4096, 1024);
  cast_x<<<16384, 256, 0, stream>>>(x, Xb, 4194304);

  // QKV projection: M=4096, N=6144, K=4096; grid 24x32 = 768 = 3 exact CU rounds
  gemm128<<<dim3(24, 32), 512, 0, stream>>>(Xb, Wqt, Qb, Kb, Vt);

  rope_ip<<<32768, 256, 0, stream>>>(Qb, 8388608);
  rope_ip<<<8192, 256, 0, stream>>>(Kb, 2097152);

  transpose_cast<<<dim3(128, 128), dim3(32, 8), 0, stream>>>(wo, Wqt, 4096, 4096);

  flash<<<dim3(32, 32, 2), 256, 0, stream>>>(Qb, Kb, Vt, Xb);

  // output projection: M=4096, N=4096, K=4096; grid 16x16 = 256 = 1 exact round
  gemm256<<<dim3(16, 16), 512, 0, stream>>>(Xb, Wqt, 4096, out);
}

// Round 4
// 806.083 us; speedup vs baseline: 1.0842x; 1.0210x over previous
//
#include <hip/hip_runtime.h>
#include <stdint.h>

typedef unsigned short u16;
using short8 = __attribute__((ext_vector_type(8))) short;
using f32x4  = __attribute__((ext_vector_type(4))) float;

#define S_LEN 2048
#define NH 32
#define NKV 8
#define HD 128
#define DIM 4096
#define NQ 4096
#define NKVD 1024

typedef __attribute__((address_space(1))) unsigned int uGLB;
typedef __attribute__((address_space(3))) unsigned int uLDS;

__device__ __forceinline__ void g2l16(const u16* g, u16* l) {
  __builtin_amdgcn_global_load_lds((const uGLB*)g, (uLDS*)l, 16, 0, 0);
}

__device__ __forceinline__ float b2f(u16 u) {
  union { unsigned u32; float f; } x; x.u32 = ((unsigned)u) << 16; return x.f;
}
__device__ __forceinline__ u16 f2b(float f) {
  union { float f; unsigned u32; } x; x.f = f;
  unsigned lsb = (x.u32 >> 16) & 1u;
  x.u32 += 0x7fffu + lsb;
  return (u16)(x.u32 >> 16);
}

// ---------------- transpose + cast: in [K][N] fp32 -> out [N][K] bf16 ----------------
__global__ __launch_bounds__(256) void transpose_cast(const float* __restrict__ in,
                                                      u16* __restrict__ out,
                                                      int K, int N) {
  __shared__ float tile[32][33];
  int n0 = blockIdx.x * 32, k0 = blockIdx.y * 32;
  int tx = threadIdx.x, ty = threadIdx.y;
#pragma unroll
  for (int j = 0; j < 4; ++j)
    tile[ty + j * 8][tx] = in[(size_t)(k0 + ty + j * 8) * N + n0 + tx];
  __syncthreads();
#pragma unroll
  for (int j = 0; j < 4; ++j)
    out[(size_t)(n0 + ty + j * 8) * K + k0 + tx] = f2b(tile[tx][ty + j * 8]);
}

__global__ __launch_bounds__(256) void cast_x(const float* __restrict__ in,
                                              u16* __restrict__ out, int n4) {
  int i = blockIdx.x * 256 + threadIdx.x;
  if (i >= n4) return;
  float4 v = reinterpret_cast<const float4*>(in)[i];
  ushort4 u;
  u.x = f2b(v.x); u.y = f2b(v.y); u.z = f2b(v.z); u.w = f2b(v.w);
  reinterpret_cast<ushort4*>(out)[i] = u;
}

// ---------------- 256x256 4-phase GEMM (out-projection), ch^(row&7) swizzle ----------------
// A [M][K] bf16, Bt [N][K] bf16, K=4096. 512 threads = 8 waves (2M x 4N).
// LDS halves [128 rows][64 cols] bf16 (128B rows, 8 chunks of 16B);
// physical chunk = logical chunk ^ (row & 7): conflict-free ds_read_b128,
// applied via pre-swizzled global source (linear global_load_lds dest) + swizzled read addr.
// XCD mapping: region-blocked (4n x 8m per XCD) so the 32 co-resident blocks of an
// XCD share operand panels in its private L2 (round-3 evidence: 93% L2 miss on the
// old row-major swizzle; fill = A 8x2MB + B 4x2MB = 24MB/XCD vs 36MB before).
__global__ __launch_bounds__(512) void gemm256(const u16* __restrict__ A,
                                               const u16* __restrict__ Bt,
                                               int N,
                                               float* __restrict__ out) {
  const int K = 4096;
  const int NT = 64;  // K / 64
  __shared__ __align__(16) u16 lds[2][2][2][8192];  // 128 KiB

  int tid  = threadIdx.x;
  int lane = tid & 63, w = tid >> 6;
  int ml   = lane & 15, quad = lane >> 4;
  int wm   = w >> 2, wn = w & 3;

  // region-blocked XCD swizzle: grid 16x16, 8 XCD regions of 4n x 8m (bijective)
  int bid = blockIdx.y * gridDim.x + blockIdx.x;
  int xcd = bid & 7, idx = bid >> 3;           // idx 0..31
  int bx = (xcd & 3) * 4 + (idx & 3);          // 0..15
  int by = (xcd >> 2) * 8 + (idx >> 2);        // 0..15
  int m0 = by * 256, n0 = bx * 256;

  // staging: physical LDS slot (row r, chunk cp) holds global chunk cg = cp ^ (r&7)
  int dstB = w * 1024 + lane * 16;                 // linear LDS byte slot (8KB segment)
  int r    = dstB >> 7;                            // row 0..63 (second load: +64, (r+64)&7==r&7)
  int cg   = ((dstB >> 4) & 7) ^ (r & 7);
  const u16* pA = A  + (size_t)(m0 + r) * K + cg * 8;
  const u16* pB = Bt + (size_t)(n0 + r) * K + cg * 8;

#define STAGE(mat, T, hh) do { \
    int _b = (T) & 1; \
    int _Tc = (T) < NT ? (T) : (NT - 1); \
    const u16* _s = ((mat) ? pB : pA) + (size_t)(hh) * 128 * K + (size_t)_Tc * 64; \
    u16* _d = &lds[_b][mat][hh][w * 512]; \
    g2l16(_s, _d); \
    g2l16(_s + (size_t)64 * K, _d + 4096); \
  } while (0)

  f32x4 acc[8][4] = {};
  int cxa  = (quad ^ (ml & 7)) << 4;               // chunk byte for ks=0; ks flips bit6
  int aoff = ml * 128 + cxa;
  int boff = (wn & 1) * 8192 + aoff;

  STAGE(0, 0, 0); STAGE(0, 0, 1); STAGE(1, 0, 0); STAGE(1, 0, 1);
  STAGE(0, 1, 0);
  asm volatile("s_waitcnt vmcnt(2)" ::: "memory");
  __builtin_amdgcn_s_barrier();

  short8 af[4][2], bf0[2][2], bf1[2][2];

  for (int t = 0; t < NT; ++t) {
    int buf = t & 1;
    const char* Ab = reinterpret_cast<const char*>(&lds[buf][0][wm][0]);
    const char* Bb = reinterpret_cast<const char*>(&lds[buf][1][wn >> 1][0]);

    // ---- P1: quadrant (mh0, nh0) ----
#pragma unroll
    for (int mi = 0; mi < 4; ++mi)
#pragma unroll
      for (int ks = 0; ks < 2; ++ks)
        af[mi][ks] = *reinterpret_cast<const short8*>(Ab + (aoff ^ (ks << 6)) + mi * 2048);
#pragma unroll
    for (int ni = 0; ni < 2; ++ni)
#pragma unroll
      for (int ks = 0; ks < 2; ++ks)
        bf0[ni][ks] = *reinterpret_cast<const short8*>(Bb + (boff ^ (ks << 6)) + ni * 2048);
    STAGE(0, t + 1, 1);
    __builtin_amdgcn_s_barrier();
    asm volatile("s_waitcnt lgkmcnt(0)" ::: "memory");
    __builtin_amdgcn_sched_barrier(0);
    __builtin_amdgcn_s_setprio(1);
#pragma unroll
    for (int mi = 0; mi < 4; ++mi)
#pragma unroll
      for (int ni = 0; ni < 2; ++ni)
#pragma unroll
        for (int ks = 0; ks < 2; ++ks)
          acc[mi][ni] = __builtin_amdgcn_mfma_f32_16x16x32_bf16(af[mi][ks], bf0[ni][ks], acc[mi][ni], 0, 0, 0);
    __builtin_amdgcn_s_setprio(0);
    __builtin_amdgcn_s_barrier();

    // ---- P2: (mh0, nh1) ----
#pragma unroll
    for (int ni = 0; ni < 2; ++ni)
#pragma unroll
      for (int ks = 0; ks < 2; ++ks)
        bf1[ni][ks] = *reinterpret_cast<const short8*>(Bb + (boff ^ (ks << 6)) + (2 + ni) * 2048);
    STAGE(1, t + 1, 0);
    __builtin_amdgcn_s_barrier();
    asm volatile("s_waitcnt lgkmcnt(0)" ::: "memory");
    __builtin_amdgcn_sched_barrier(0);
    __builtin_amdgcn_s_setprio(1);
#pragma unroll
    for (int mi = 0; mi < 4; ++mi)
#pragma unroll
      for (int ni = 0; ni < 2; ++ni)
#pragma unroll
        for (int ks = 0; ks < 2; ++ks)
          acc[mi][2 + ni] = __builtin_amdgcn_mfma_f32_16x16x32_bf16(af[mi][ks], bf1[ni][ks], acc[mi][2 + ni], 0, 0, 0);
    __builtin_amdgcn_s_setprio(0);
    __builtin_amdgcn_s_barrier();

    // ---- P3: (mh1, nh0) ----
#pragma unroll
    for (int mi = 0; mi < 4; ++mi)
#pragma unroll
      for (int ks = 0; ks < 2; ++ks)
        af[mi][ks] = *reinterpret_cast<const short8*>(Ab + 8192 + (aoff ^ (ks << 6)) + mi * 2048);
    STAGE(1, t + 1, 1);
    __builtin_amdgcn_s_barrier();
    asm volatile("s_waitcnt lgkmcnt(0)" ::: "memory");
    __builtin_amdgcn_sched_barrier(0);
    __builtin_amdgcn_s_setprio(1);
#pragma unroll
    for (int mi = 0; mi < 4; ++mi)
#pragma unroll
      for (int ni = 0; ni < 2; ++ni)
#pragma unroll
        for (int ks = 0; ks < 2; ++ks)
          acc[4 + mi][ni] = __builtin_amdgcn_mfma_f32_16x16x32_bf16(af[mi][ks], bf0[ni][ks], acc[4 + mi][ni], 0, 0, 0);
    __builtin_amdgcn_s_setprio(0);
    __builtin_amdgcn_s_barrier();

    // ---- P4: (mh1, nh1); stage (t+2,A0) into CURRENT buf (A reads done in P3) ----
    STAGE(0, t + 2, 0);
    __builtin_amdgcn_s_barrier();
    __builtin_amdgcn_s_setprio(1);
#pragma unroll
    for (int mi = 0; mi < 4; ++mi)
#pragma unroll
      for (int ni = 0; ni < 2; ++ni)
#pragma unroll
        for (int ks = 0; ks < 2; ++ks)
          acc[4 + mi][2 + ni] = __builtin_amdgcn_mfma_f32_16x16x32_bf16(af[mi][ks], bf1[ni][ks], acc[4 + mi][2 + ni], 0, 0, 0);
    __builtin_amdgcn_s_setprio(0);
    asm volatile("s_waitcnt vmcnt(2)" ::: "memory");
    __builtin_amdgcn_s_barrier();
  }
#undef STAGE

#pragma unroll
  for (int mi = 0; mi < 8; ++mi) {
#pragma unroll
    for (int ni = 0; ni < 4; ++ni) {
#pragma unroll
      for (int rr = 0; rr < 4; ++rr) {
        int row = m0 + wm * 128 + mi * 16 + quad * 4 + rr;
        int col = n0 + wn * 64 + ni * 16 + ml;
        out[(size_t)row * N + col] = acc[mi][ni][rr];
      }
    }
  }
}

// ---------------- 128x256 2-phase GEMM (QKV projection + scatter) ----------------
// grid (24, 32) = 768 blocks = 3 exact rounds of 256 CUs. 96 KiB LDS, 8 waves (2M x 4N),
// wave tile 64x64, 16 MFMA per phase. Same ch^(row&7) swizzle as gemm256.
// Leads: A(t+1) staged in P1 (other buf); B(t+2) staged in P2 into CURRENT buf
// (safe: all B reads issue in P1 and drain at P1's lgkmcnt(0) before its barrier).
// XCD mapping: region-blocked (6n x 16m per XCD), n-inner order. Concurrent window
// per XCD = ~6n x 6m -> per-k-step L2 misses ~0.29MB vs 1.5MB demand (round-3: the
// row-major swizzle gave 93% miss, FETCH 720MB, and dur == bytes/3.1TB/s).
__global__ __launch_bounds__(512) void gemm128(const u16* __restrict__ A,
                                               const u16* __restrict__ Bt,
                                               u16* __restrict__ Qb,
                                               u16* __restrict__ Kb,
                                               u16* __restrict__ Vt) {
  const int K = 4096;
  const int NT = 64;
  // LDS byte map: A(b,h) = b*16384 + h*8192 (2x2x[64][64] = 32KB)
  //               B(b,h) = 32768 + b*32768 + h*16384 (2x2x[128][64] = 64KB)
  __shared__ __align__(16) char L[98304];

  int tid  = threadIdx.x;
  int lane = tid & 63, w = tid >> 6;
  int ml   = lane & 15, quad = lane >> 4;
  int wm   = w >> 2, wn = w & 3;

  // region-blocked XCD swizzle: grid 24x32, 8 XCD regions of 6n x 16m (bijective)
  int bid = blockIdx.y * gridDim.x + blockIdx.x;
  int xcd = bid & 7, idx = bid >> 3;           // idx 0..95
  int bx = (xcd & 3) * 6 + idx % 6;            // 0..23
  int by = (xcd >> 2) * 16 + idx / 6;          // 0..31
  int m0 = by * 128, n0 = bx * 256;

  int dstB = w * 1024 + lane * 16;
  int r    = dstB >> 7;              // 0..63
  int cg   = ((dstB >> 4) & 7) ^ (r & 7);
  const u16* pA = A  + (size_t)(m0 + r) * K + cg * 8;
  const u16* pB = Bt + (size_t)(n0 + r) * K + cg * 8;

#define STAGE_A(T, h) do { \
    int _b = (T) & 1; int _Tc = (T) < NT ? (T) : (NT - 1); \
    g2l16(pA + (size_t)(h) * 64 * K + (size_t)_Tc * 64, \
          (u16*)(L + _b * 16384 + (h) * 8192 + w * 1024)); \
  } while (0)
#define STAGE_B(T, h) do { \
    int _b = (T) & 1; int _Tc = (T) < NT ? (T) : (NT - 1); \
    const u16* _s = pB + (size_t)(h) * 128 * K + (size_t)_Tc * 64; \
    char* _d = L + 32768 + _b * 32768 + (h) * 16384 + w * 1024; \
    g2l16(_s, (u16*)_d); \
    g2l16(_s + (size_t)64 * K, (u16*)(_d + 8192)); \
  } while (0)

  f32x4 acc[4][4] = {};
  int cxa  = (quad ^ (ml & 7)) << 4;
  int aoff = ml * 128 + cxa;
  int boff = (wn & 1) * 8192 + aoff;

  // prologue: tile0 (6 loads) + B(1) (4 loads, long lead); drain tile0
  STAGE_A(0, 0); STAGE_A(0, 1); STAGE_B(0, 0); STAGE_B(0, 1);
  STAGE_B(1, 0); STAGE_B(1, 1);
  asm volatile("s_waitcnt vmcnt(4)" ::: "memory");
  __builtin_amdgcn_s_barrier();

  short8 af[2][2], af2[2][2], bf[4][2];

  for (int t = 0; t < NT; ++t) {
    int buf = t & 1;
    const char* Ab = L + buf * 16384 + wm * 8192;
    const char* Bb = L + 32768 + buf * 32768 + (wn >> 1) * 16384;

    // ---- P1: wave rows 0..31, all 64 n-cols; reads af(4) + bf(8) ----
#pragma unroll
    for (int mi = 0; mi < 2; ++mi)
#pragma unroll
      for (int ks = 0; ks < 2; ++ks)
        af[mi][ks] = *reinterpret_cast<const short8*>(Ab + (aoff ^ (ks << 6)) + mi * 2048);
#pragma unroll
    for (int ni = 0; ni < 4; ++ni)
#pragma unroll
      for (int ks = 0; ks < 2; ++ks)
        bf[ni][ks] = *reinterpret_cast<const short8*>(Bb + (boff ^ (ks << 6)) + ni * 2048);
    STAGE_A(t + 1, 0); STAGE_A(t + 1, 1);   // other buffer
    __builtin_amdgcn_s_barrier();
    asm volatile("s_waitcnt lgkmcnt(0)" ::: "memory");
    __builtin_amdgcn_sched_barrier(0);
    __builtin_amdgcn_s_setprio(1);
#pragma unroll
    for (int mi = 0; mi < 2; ++mi)
#pragma unroll
      for (int ni = 0; ni < 4; ++ni)
#pragma unroll
        for (int ks = 0; ks < 2; ++ks)
          acc[mi][ni] = __builtin_amdgcn_mfma_f32_16x16x32_bf16(af[mi][ks], bf[ni][ks], acc[mi][ni], 0, 0, 0);
    __builtin_amdgcn_s_setprio(0);
    __builtin_amdgcn_s_barrier();

    // ---- P2: wave rows 32..63; reads af2(4); stage B(t+2) into CURRENT buf ----
#pragma unroll
    for (int mi = 0; mi < 2; ++mi)
#pragma unroll
      for (int ks = 0; ks < 2; ++ks)
        af2[mi][ks] = *reinterpret_cast<const short8*>(Ab + 4096 + (aoff ^ (ks << 6)) + mi * 2048);
    STAGE_B(t + 2, 0); STAGE_B(t + 2, 1);
    __builtin_amdgcn_s_barrier();
    asm volatile("s_waitcnt lgkmcnt(0)" ::: "memory");
    __builtin_amdgcn_sched_barrier(0);
    __builtin_amdgcn_s_setprio(1);
#pragma unroll
    for (int mi = 0; mi < 2; ++mi)
#pragma unroll
      for (int ni = 0; ni < 4; ++ni)
#pragma unroll
        for (int ks = 0; ks < 2; ++ks)
          acc[2 + mi][ni] = __builtin_amdgcn_mfma_f32_16x16x32_bf16(af2[mi][ks], bf[ni][ks], acc[2 + mi][ni], 0, 0, 0);
    __builtin_amdgcn_s_setprio(0);
    // counted drain: leave only B(t+2)'s 4 loads in flight -> tile t+1 resident
    asm volatile("s_waitcnt vmcnt(4)" ::: "memory");
    __builtin_amdgcn_s_barrier();
  }
#undef STAGE_A
#undef STAGE_B

  // epilogue: scatter to Qb/Kb/Vt (bf16)
#pragma unroll
  for (int a = 0; a < 4; ++a) {
#pragma unroll
    for (int ni = 0; ni < 4; ++ni) {
#pragma unroll
      for (int rr = 0; rr < 4; ++rr) {
        int row = m0 + wm * 64 + a * 16 + quad * 4 + rr;
        int col = n0 + wn * 64 + ni * 16 + ml;
        float v = acc[a][ni][rr];
        int b = row >> 11, s = row & (S_LEN - 1);
        if (col < NQ) {
          int h = col >> 7, d = col & 127;
          Qb[((size_t)((b * NH + h) * S_LEN + s)) * HD + d] = f2b(v);
        } else if (col < NQ + NKVD) {
          int cc = col - NQ; int h = cc >> 7, d = cc & 127;
          Kb[((size_t)((b * NKV + h) * S_LEN + s)) * HD + d] = f2b(v);
        } else {
          int cc = col - NQ - NKVD; int h = cc >> 7, d = cc & 127;
          Vt[((size_t)((b * NKV + h) * HD + d)) * S_LEN + s] = f2b(v);
        }
      }
    }
  }
}

// ---------------- RoPE in-place ----------------
__global__ __launch_bounds__(256) void rope_ip(u16* __restrict__ X, int npairs) {
  int idx = blockIdx.x * 256 + threadIdx.x;
  if (idx >= npairs) return;
  int i = idx & 63;
  int s = (idx >> 6) & (S_LEN - 1);
  float inv = __expf(-0.2050369278939421f * (float)i);
  float ang = (float)s * inv;
  float sn, cs;
  sincosf(ang, &sn, &cs);
  ushort2 pr = reinterpret_cast<ushort2*>(X)[idx];
  float a = b2f(pr.x), b = b2f(pr.y);
  ushort2 o;
  o.x = f2b(a * cs - b * sn);
  o.y = f2b(a * sn + b * cs);
  reinterpret_cast<ushort2*>(X)[idx] = o;
}

// ---------------- flash attention (S^T orientation, fixed-max, DMA staging) ----------------
__global__ __launch_bounds__(256, 3) void flash(const u16* __restrict__ Qb,
                                                const u16* __restrict__ Kb,
                                                const u16* __restrict__ Vt,
                                                u16* __restrict__ AO) {
  __shared__ __align__(16) u16 Ks[64 * 128];   // [row k][chunk'=chunk^ (row&15)], 16 chunks
  __shared__ __align__(16) u16 Vs[128 * 64];   // [row d][chunk'=chunk^(row&7)], 8 chunks
  __shared__ __align__(16) u16 Ps[4 * 16 * 80];  // per-wave [q=16][k=64 pad->80]

  int tid  = threadIdx.x;
  int lane = tid & 63, w = tid >> 6;
  int ml   = lane & 15, quad = lane >> 4;
  int q_tile = blockIdx.x, h = blockIdx.y, b = blockIdx.z;
  int hkv = h >> 2;
  int q0  = q_tile * 64;
  const u16* Qh = Qb + ((size_t)(b * NH + h) * S_LEN) * HD;
  const u16* Kh = Kb + ((size_t)(b * NKV + hkv) * S_LEN) * HD;
  const u16* Vh = Vt + ((size_t)(b * NKV + hkv) * HD) * S_LEN;
  u16* Pw = Ps + w * 16 * 80;

  // hoist Q B-fragments (lane = q row, quad packs k)
  short8 qf[4];
#pragma unroll
  for (int ks = 0; ks < 4; ++ks)
    qf[ks] = *reinterpret_cast<const short8*>(
        Qh + (size_t)(q0 + w * 16 + ml) * HD + ks * 32 + quad * 8);

  short8 ones8;
  {
    u16 one_b = 0x3f80;
#pragma unroll
    for (int j = 0; j < 8; ++j) ones8[j] = (short)one_b;
  }

  f32x4 o[8] = {};
  f32x4 o9 = {};
  const float SC = 0.12751745f;  // (1/sqrt(128)) * log2(e)
  const float BIAS = 18.0f;

  int qg = q0 + w * 16 + ml;
  int ntile = q_tile + 1;
  for (int it = 0; it < ntile; ++it) {
    int kv0 = it * 64;
    __syncthreads();
    // stage K tile (64 x 128) and V tile (128 x 64) via DMA, swizzled
#pragma unroll
    for (int p = 0; p < 4; ++p) {
      int slot = w * 256 + p * 64 + lane;
      int krow = slot >> 4, kch = slot & 15;
      int ksrc = kch ^ (krow & 15);
      g2l16(Kh + (size_t)(kv0 + krow) * HD + ksrc * 8, &Ks[(w * 256 + p * 64) * 8]);
      int vrow = slot >> 3, vch = slot & 7;
      int vsrc = vch ^ (vrow & 7);
      g2l16(Vh + (size_t)vrow * S_LEN + kv0 + vsrc * 8, &Vs[(w * 256 + p * 64) * 8]);
    }
    __syncthreads();

    // S^T tiles: mfma(A=K rows, B=Q rows) -> C[k][q], col=q=ml, row=k=quad*4+r
    f32x4 st[4] = {};
#pragma unroll
    for (int ks = 0; ks < 4; ++ks) {
#pragma unroll
      for (int nt = 0; nt < 4; ++nt) {
        int row = nt * 16 + ml;
        int ch = ((ks << 2) | quad) ^ ml;
        short8 kf = *reinterpret_cast<const short8*>(&Ks[row * 128 + ch * 8]);
        st[nt] = __builtin_amdgcn_mfma_f32_16x16x32_bf16(kf, qf[ks], st[nt], 0, 0, 0);
      }
    }

    bool diag = (it == q_tile);
#pragma unroll
    for (int nt = 0; nt < 4; ++nt) {
      float p0 = exp2f(fmaf(st[nt][0], SC, -BIAS));
      float p1 = exp2f(fmaf(st[nt][1], SC, -BIAS));
      float p2 = exp2f(fmaf(st[nt][2], SC, -BIAS));
      float p3 = exp2f(fmaf(st[nt][3], SC, -BIAS));
      if (diag) {
        int kg = kv0 + nt * 16 + quad * 4;
        if (kg + 0 > qg) p0 = 0.f;
        if (kg + 1 > qg) p1 = 0.f;
        if (kg + 2 > qg) p2 = 0.f;
        if (kg + 3 > qg) p3 = 0.f;
      }
      uint2 pk;
      pk.x = (unsigned)f2b(p0) | ((unsigned)f2b(p1) << 16);
      pk.y = (unsigned)f2b(p2) | ((unsigned)f2b(p3) << 16);
      *reinterpret_cast<uint2*>(&Pw[ml * 80 + nt * 16 + quad * 4]) = pk;
    }
    // wave-private Ps: no barrier needed (lgkmcnt wait auto-inserted)

#pragma unroll
    for (int ks2 = 0; ks2 < 2; ++ks2) {
      short8 pf = *reinterpret_cast<const short8*>(&Pw[ml * 80 + ks2 * 32 + quad * 8]);
#pragma unroll
      for (int dt = 0; dt < 8; ++dt) {
        int row = dt * 16 + ml;
        int ch = ((ks2 << 2) | quad) ^ (ml & 7);
        short8 vf = *reinterpret_cast<const short8*>(&Vs[row * 64 + ch * 8]);
        o[dt] = __builtin_amdgcn_mfma_f32_16x16x32_bf16(pf, vf, o[dt], 0, 0, 0);
      }
      o9 = __builtin_amdgcn_mfma_f32_16x16x32_bf16(pf, ones8, o9, 0, 0, 0);
    }
  }

  size_t row_base = (size_t)(b * S_LEN + q0 + w * 16 + quad * 4);
#pragma unroll
  for (int rr = 0; rr < 4; ++rr) {
    float inv_l = 1.0f / o9[rr];
#pragma unroll
    for (int dt = 0; dt < 8; ++dt) {
      int col = h * HD + dt * 16 + ml;
      AO[(row_base + rr) * (size_t)DIM + col] = f2b(o[dt][rr] * inv_l);
    }
  }
}

extern "C" void kernel_launch(void* const* d_in, const int* in_sizes, int n_in,
                              void* d_out, int out_size, void* d_ws, size_t ws_size,
                              hipStream_t stream) {
  const float* x  = (const float*)d_in[0];
  const float* wq = (const float*)d_in[1];
  const float* wk = (const float*)d_in[2];
  const float* wv = (const float*)d_in[3];
  const float* wo = (const float*)d_in[4];
  float* out = (float*)d_out;
  char* ws = (char*)d_ws;

  u16* Wqt = (u16*)(ws + 0);          // [4096][4096], later wo^T
  u16* Wkt = (u16*)(ws + 33554432);   // [1024][4096]
  u16* Wvt = (u16*)(ws + 41943040);   // [1024][4096]
  u16* Xb  = (u16*)(ws + 50331648);   // [4096][4096] bf16, later AO
  u16* Qb  = (u16*)(ws + 83886080);
  u16* Kb  = (u16*)(ws + 117440512);
  u16* Vt  = (u16*)(ws + 125829120);

  transpose_cast<<<dim3(128, 128), dim3(32, 8), 0, stream>>>(wq, Wqt, 4096, 4096);
  transpose_cast<<<dim3(32, 128),  dim3(32, 8), 0, stream>>>(wk, Wkt, 4096, 1024);
  transpose_cast<<<dim3(32, 128),  dim3(32, 8), 0, stream>>>(wv, Wvt, 4096, 1024);
  cast_x<<<16384, 256, 0, stream>>>(x, Xb, 4194304);

  // QKV projection: M=4096, N=6144, K=4096; grid 24x32 = 768 = 3 exact CU rounds
  gemm128<<<dim3(24, 32), 512, 0, stream>>>(Xb, Wqt, Qb, Kb, Vt);

  rope_ip<<<32768, 256, 0, stream>>>(Qb, 8388608);
  rope_ip<<<8192, 256, 0, stream>>>(Kb, 2097152);

  transpose_cast<<<dim3(128, 128), dim3(32, 8), 0, stream>>>(wo, Wqt, 4096, 4096);

  flash<<<dim3(32, 32, 2), 256, 0, stream>>>(Qb, Kb, Vt, Xb);

  // output projection: M=4096, N=4096, K=4096; grid 16x16 = 256 = 1 exact round
  gemm256<<<dim3(16, 16), 512, 0, stream>>>(Xb, Wqt, 4096, out);
}

// Round 6
// 800.888 us; speedup vs baseline: 1.0912x; 1.0065x over previous
//
#include <hip/hip_runtime.h>
#include <stdint.h>

typedef unsigned short u16;
using short8 = __attribute__((ext_vector_type(8))) short;
using f32x4  = __attribute__((ext_vector_type(4))) float;

#define S_LEN 2048
#define NH 32
#define NKV 8
#define HD 128
#define DIM 4096
#define NQ 4096
#define NKVD 1024

typedef __attribute__((address_space(1))) unsigned int uGLB;
typedef __attribute__((address_space(3))) unsigned int uLDS;

__device__ __forceinline__ void g2l16(const u16* g, u16* l) {
  __builtin_amdgcn_global_load_lds((const uGLB*)g, (uLDS*)l, 16, 0, 0);
}

__device__ __forceinline__ float b2f(u16 u) {
  union { unsigned u32; float f; } x; x.u32 = ((unsigned)u) << 16; return x.f;
}
__device__ __forceinline__ u16 f2b(float f) {
  union { float f; unsigned u32; } x; x.f = f;
  unsigned lsb = (x.u32 >> 16) & 1u;
  x.u32 += 0x7fffu + lsb;
  return (u16)(x.u32 >> 16);
}

// ---------------- transpose + cast: in [K][N] fp32 -> out [N][K] bf16 ----------------
__global__ __launch_bounds__(256) void transpose_cast(const float* __restrict__ in,
                                                      u16* __restrict__ out,
                                                      int K, int N) {
  __shared__ float tile[32][33];
  int n0 = blockIdx.x * 32, k0 = blockIdx.y * 32;
  int tx = threadIdx.x, ty = threadIdx.y;
#pragma unroll
  for (int j = 0; j < 4; ++j)
    tile[ty + j * 8][tx] = in[(size_t)(k0 + ty + j * 8) * N + n0 + tx];
  __syncthreads();
#pragma unroll
  for (int j = 0; j < 4; ++j)
    out[(size_t)(n0 + ty + j * 8) * K + k0 + tx] = f2b(tile[tx][ty + j * 8]);
}

__global__ __launch_bounds__(256) void cast_x(const float* __restrict__ in,
                                              u16* __restrict__ out, int n4) {
  int i = blockIdx.x * 256 + threadIdx.x;
  if (i >= n4) return;
  float4 v = reinterpret_cast<const float4*>(in)[i];
  ushort4 u;
  u.x = f2b(v.x); u.y = f2b(v.y); u.z = f2b(v.z); u.w = f2b(v.w);
  reinterpret_cast<ushort4*>(out)[i] = u;
}

// ---------------- 256x256 4-phase GEMM (out-projection), ch^(row&7) swizzle ----------------
// (unchanged — frozen for attribution)
__global__ __launch_bounds__(512) void gemm256(const u16* __restrict__ A,
                                               const u16* __restrict__ Bt,
                                               int N,
                                               float* __restrict__ out) {
  const int K = 4096;
  const int NT = 64;  // K / 64
  __shared__ __align__(16) u16 lds[2][2][2][8192];  // 128 KiB

  int tid  = threadIdx.x;
  int lane = tid & 63, w = tid >> 6;
  int ml   = lane & 15, quad = lane >> 4;
  int wm   = w >> 2, wn = w & 3;

  // region-blocked XCD swizzle: grid 16x16, 8 XCD regions of 4n x 8m (bijective)
  int bid = blockIdx.y * gridDim.x + blockIdx.x;
  int xcd = bid & 7, idx = bid >> 3;           // idx 0..31
  int bx = (xcd & 3) * 4 + (idx & 3);          // 0..15
  int by = (xcd >> 2) * 8 + (idx >> 2);        // 0..15
  int m0 = by * 256, n0 = bx * 256;

  // staging: physical LDS slot (row r, chunk cp) holds global chunk cg = cp ^ (r&7)
  int dstB = w * 1024 + lane * 16;                 // linear LDS byte slot (8KB segment)
  int r    = dstB >> 7;                            // row 0..63 (second load: +64, (r+64)&7==r&7)
  int cg   = ((dstB >> 4) & 7) ^ (r & 7);
  const u16* pA = A  + (size_t)(m0 + r) * K + cg * 8;
  const u16* pB = Bt + (size_t)(n0 + r) * K + cg * 8;

#define STAGE(mat, T, hh) do { \
    int _b = (T) & 1; \
    int _Tc = (T) < NT ? (T) : (NT - 1); \
    const u16* _s = ((mat) ? pB : pA) + (size_t)(hh) * 128 * K + (size_t)_Tc * 64; \
    u16* _d = &lds[_b][mat][hh][w * 512]; \
    g2l16(_s, _d); \
    g2l16(_s + (size_t)64 * K, _d + 4096); \
  } while (0)

  f32x4 acc[8][4] = {};
  int cxa  = (quad ^ (ml & 7)) << 4;               // chunk byte for ks=0; ks flips bit6
  int aoff = ml * 128 + cxa;
  int boff = (wn & 1) * 8192 + aoff;

  STAGE(0, 0, 0); STAGE(0, 0, 1); STAGE(1, 0, 0); STAGE(1, 0, 1);
  STAGE(0, 1, 0);
  asm volatile("s_waitcnt vmcnt(2)" ::: "memory");
  __builtin_amdgcn_s_barrier();

  short8 af[4][2], bf0[2][2], bf1[2][2];

  for (int t = 0; t < NT; ++t) {
    int buf = t & 1;
    const char* Ab = reinterpret_cast<const char*>(&lds[buf][0][wm][0]);
    const char* Bb = reinterpret_cast<const char*>(&lds[buf][1][wn >> 1][0]);

    // ---- P1: quadrant (mh0, nh0) ----
#pragma unroll
    for (int mi = 0; mi < 4; ++mi)
#pragma unroll
      for (int ks = 0; ks < 2; ++ks)
        af[mi][ks] = *reinterpret_cast<const short8*>(Ab + (aoff ^ (ks << 6)) + mi * 2048);
#pragma unroll
    for (int ni = 0; ni < 2; ++ni)
#pragma unroll
      for (int ks = 0; ks < 2; ++ks)
        bf0[ni][ks] = *reinterpret_cast<const short8*>(Bb + (boff ^ (ks << 6)) + ni * 2048);
    STAGE(0, t + 1, 1);
    __builtin_amdgcn_s_barrier();
    asm volatile("s_waitcnt lgkmcnt(0)" ::: "memory");
    __builtin_amdgcn_sched_barrier(0);
    __builtin_amdgcn_s_setprio(1);
#pragma unroll
    for (int mi = 0; mi < 4; ++mi)
#pragma unroll
      for (int ni = 0; ni < 2; ++ni)
#pragma unroll
        for (int ks = 0; ks < 2; ++ks)
          acc[mi][ni] = __builtin_amdgcn_mfma_f32_16x16x32_bf16(af[mi][ks], bf0[ni][ks], acc[mi][ni], 0, 0, 0);
    __builtin_amdgcn_s_setprio(0);
    __builtin_amdgcn_s_barrier();

    // ---- P2: (mh0, nh1) ----
#pragma unroll
    for (int ni = 0; ni < 2; ++ni)
#pragma unroll
      for (int ks = 0; ks < 2; ++ks)
        bf1[ni][ks] = *reinterpret_cast<const short8*>(Bb + (boff ^ (ks << 6)) + (2 + ni) * 2048);
    STAGE(1, t + 1, 0);
    __builtin_amdgcn_s_barrier();
    asm volatile("s_waitcnt lgkmcnt(0)" ::: "memory");
    __builtin_amdgcn_sched_barrier(0);
    __builtin_amdgcn_s_setprio(1);
#pragma unroll
    for (int mi = 0; mi < 4; ++mi)
#pragma unroll
      for (int ni = 0; ni < 2; ++ni)
#pragma unroll
        for (int ks = 0; ks < 2; ++ks)
          acc[mi][2 + ni] = __builtin_amdgcn_mfma_f32_16x16x32_bf16(af[mi][ks], bf1[ni][ks], acc[mi][2 + ni], 0, 0, 0);
    __builtin_amdgcn_s_setprio(0);
    __builtin_amdgcn_s_barrier();

    // ---- P3: (mh1, nh0) ----
#pragma unroll
    for (int mi = 0; mi < 4; ++mi)
#pragma unroll
      for (int ks = 0; ks < 2; ++ks)
        af[mi][ks] = *reinterpret_cast<const short8*>(Ab + 8192 + (aoff ^ (ks << 6)) + mi * 2048);
    STAGE(1, t + 1, 1);
    __builtin_amdgcn_s_barrier();
    asm volatile("s_waitcnt lgkmcnt(0)" ::: "memory");
    __builtin_amdgcn_sched_barrier(0);
    __builtin_amdgcn_s_setprio(1);
#pragma unroll
    for (int mi = 0; mi < 4; ++mi)
#pragma unroll
      for (int ni = 0; ni < 2; ++ni)
#pragma unroll
        for (int ks = 0; ks < 2; ++ks)
          acc[4 + mi][ni] = __builtin_amdgcn_mfma_f32_16x16x32_bf16(af[mi][ks], bf0[ni][ks], acc[4 + mi][ni], 0, 0, 0);
    __builtin_amdgcn_s_setprio(0);
    __builtin_amdgcn_s_barrier();

    // ---- P4: (mh1, nh1); stage (t+2,A0) into CURRENT buf (A reads done in P3) ----
    STAGE(0, t + 2, 0);
    __builtin_amdgcn_s_barrier();
    __builtin_amdgcn_s_setprio(1);
#pragma unroll
    for (int mi = 0; mi < 4; ++mi)
#pragma unroll
      for (int ni = 0; ni < 2; ++ni)
#pragma unroll
        for (int ks = 0; ks < 2; ++ks)
          acc[4 + mi][2 + ni] = __builtin_amdgcn_mfma_f32_16x16x32_bf16(af[mi][ks], bf1[ni][ks], acc[4 + mi][2 + ni], 0, 0, 0);
    __builtin_amdgcn_s_setprio(0);
    asm volatile("s_waitcnt vmcnt(2)" ::: "memory");
    __builtin_amdgcn_s_barrier();
  }
#undef STAGE

#pragma unroll
  for (int mi = 0; mi < 8; ++mi) {
#pragma unroll
    for (int ni = 0; ni < 4; ++ni) {
#pragma unroll
      for (int rr = 0; rr < 4; ++rr) {
        int row = m0 + wm * 128 + mi * 16 + quad * 4 + rr;
        int col = n0 + wn * 64 + ni * 16 + ml;
        out[(size_t)row * N + col] = acc[mi][ni][rr];
      }
    }
  }
}

// ---------------- 128x256 2-phase GEMM (QKV projection + scatter) ----------------
// (unchanged — frozen for attribution; known schedule-bound at 794 TF)
__global__ __launch_bounds__(512) void gemm128(const u16* __restrict__ A,
                                               const u16* __restrict__ Bt,
                                               u16* __restrict__ Qb,
                                               u16* __restrict__ Kb,
                                               u16* __restrict__ Vt) {
  const int K = 4096;
  const int NT = 64;
  __shared__ __align__(16) char L[98304];

  int tid  = threadIdx.x;
  int lane = tid & 63, w = tid >> 6;
  int ml   = lane & 15, quad = lane >> 4;
  int wm   = w >> 2, wn = w & 3;

  // region-blocked XCD swizzle: grid 24x32, 8 XCD regions of 6n x 16m (bijective)
  int bid = blockIdx.y * gridDim.x + blockIdx.x;
  int xcd = bid & 7, idx = bid >> 3;           // idx 0..95
  int bx = (xcd & 3) * 6 + idx % 6;            // 0..23
  int by = (xcd >> 2) * 16 + idx / 6;          // 0..31
  int m0 = by * 128, n0 = bx * 256;

  int dstB = w * 1024 + lane * 16;
  int r    = dstB >> 7;              // 0..63
  int cg   = ((dstB >> 4) & 7) ^ (r & 7);
  const u16* pA = A  + (size_t)(m0 + r) * K + cg * 8;
  const u16* pB = Bt + (size_t)(n0 + r) * K + cg * 8;

#define STAGE_A(T, h) do { \
    int _b = (T) & 1; int _Tc = (T) < NT ? (T) : (NT - 1); \
    g2l16(pA + (size_t)(h) * 64 * K + (size_t)_Tc * 64, \
          (u16*)(L + _b * 16384 + (h) * 8192 + w * 1024)); \
  } while (0)
#define STAGE_B(T, h) do { \
    int _b = (T) & 1; int _Tc = (T) < NT ? (T) : (NT - 1); \
    const u16* _s = pB + (size_t)(h) * 128 * K + (size_t)_Tc * 64; \
    char* _d = L + 32768 + _b * 32768 + (h) * 16384 + w * 1024; \
    g2l16(_s, (u16*)_d); \
    g2l16(_s + (size_t)64 * K, (u16*)(_d + 8192)); \
  } while (0)

  f32x4 acc[4][4] = {};
  int cxa  = (quad ^ (ml & 7)) << 4;
  int aoff = ml * 128 + cxa;
  int boff = (wn & 1) * 8192 + aoff;

  STAGE_A(0, 0); STAGE_A(0, 1); STAGE_B(0, 0); STAGE_B(0, 1);
  STAGE_B(1, 0); STAGE_B(1, 1);
  asm volatile("s_waitcnt vmcnt(4)" ::: "memory");
  __builtin_amdgcn_s_barrier();

  short8 af[2][2], af2[2][2], bf[4][2];

  for (int t = 0; t < NT; ++t) {
    int buf = t & 1;
    const char* Ab = L + buf * 16384 + wm * 8192;
    const char* Bb = L + 32768 + buf * 32768 + (wn >> 1) * 16384;

    // ---- P1 ----
#pragma unroll
    for (int mi = 0; mi < 2; ++mi)
#pragma unroll
      for (int ks = 0; ks < 2; ++ks)
        af[mi][ks] = *reinterpret_cast<const short8*>(Ab + (aoff ^ (ks << 6)) + mi * 2048);
#pragma unroll
    for (int ni = 0; ni < 4; ++ni)
#pragma unroll
      for (int ks = 0; ks < 2; ++ks)
        bf[ni][ks] = *reinterpret_cast<const short8*>(Bb + (boff ^ (ks << 6)) + ni * 2048);
    STAGE_A(t + 1, 0); STAGE_A(t + 1, 1);   // other buffer
    __builtin_amdgcn_s_barrier();
    asm volatile("s_waitcnt lgkmcnt(0)" ::: "memory");
    __builtin_amdgcn_sched_barrier(0);
    __builtin_amdgcn_s_setprio(1);
#pragma unroll
    for (int mi = 0; mi < 2; ++mi)
#pragma unroll
      for (int ni = 0; ni < 4; ++ni)
#pragma unroll
        for (int ks = 0; ks < 2; ++ks)
          acc[mi][ni] = __builtin_amdgcn_mfma_f32_16x16x32_bf16(af[mi][ks], bf[ni][ks], acc[mi][ni], 0, 0, 0);
    __builtin_amdgcn_s_setprio(0);
    __builtin_amdgcn_s_barrier();

    // ---- P2 ----
#pragma unroll
    for (int mi = 0; mi < 2; ++mi)
#pragma unroll
      for (int ks = 0; ks < 2; ++ks)
        af2[mi][ks] = *reinterpret_cast<const short8*>(Ab + 4096 + (aoff ^ (ks << 6)) + mi * 2048);
    STAGE_B(t + 2, 0); STAGE_B(t + 2, 1);
    __builtin_amdgcn_s_barrier();
    asm volatile("s_waitcnt lgkmcnt(0)" ::: "memory");
    __builtin_amdgcn_sched_barrier(0);
    __builtin_amdgcn_s_setprio(1);
#pragma unroll
    for (int mi = 0; mi < 2; ++mi)
#pragma unroll
      for (int ni = 0; ni < 4; ++ni)
#pragma unroll
        for (int ks = 0; ks < 2; ++ks)
          acc[2 + mi][ni] = __builtin_amdgcn_mfma_f32_16x16x32_bf16(af2[mi][ks], bf[ni][ks], acc[2 + mi][ni], 0, 0, 0);
    __builtin_amdgcn_s_setprio(0);
    asm volatile("s_waitcnt vmcnt(4)" ::: "memory");
    __builtin_amdgcn_s_barrier();
  }
#undef STAGE_A
#undef STAGE_B

#pragma unroll
  for (int a = 0; a < 4; ++a) {
#pragma unroll
    for (int ni = 0; ni < 4; ++ni) {
#pragma unroll
      for (int rr = 0; rr < 4; ++rr) {
        int row = m0 + wm * 64 + a * 16 + quad * 4 + rr;
        int col = n0 + wn * 64 + ni * 16 + ml;
        float v = acc[a][ni][rr];
        int b = row >> 11, s = row & (S_LEN - 1);
        if (col < NQ) {
          int h = col >> 7, d = col & 127;
          Qb[((size_t)((b * NH + h) * S_LEN + s)) * HD + d] = f2b(v);
        } else if (col < NQ + NKVD) {
          int cc = col - NQ; int h = cc >> 7, d = cc & 127;
          Kb[((size_t)((b * NKV + h) * S_LEN + s)) * HD + d] = f2b(v);
        } else {
          int cc = col - NQ - NKVD; int h = cc >> 7, d = cc & 127;
          Vt[((size_t)((b * NKV + h) * HD + d)) * S_LEN + s] = f2b(v);
        }
      }
    }
  }
}

// ---------------- RoPE in-place ----------------
__global__ __launch_bounds__(256) void rope_ip(u16* __restrict__ X, int npairs) {
  int idx = blockIdx.x * 256 + threadIdx.x;
  if (idx >= npairs) return;
  int i = idx & 63;
  int s = (idx >> 6) & (S_LEN - 1);
  float inv = __expf(-0.2050369278939421f * (float)i);
  float ang = (float)s * inv;
  float sn, cs;
  sincosf(ang, &sn, &cs);
  ushort2 pr = reinterpret_cast<ushort2*>(X)[idx];
  float a = b2f(pr.x), b = b2f(pr.y);
  ushort2 o;
  o.x = f2b(a * cs - b * sn);
  o.y = f2b(a * sn + b * cs);
  reinterpret_cast<ushort2*>(X)[idx] = o;
}

// ---------------- flash attention: double-buffered KV pipeline ----------------
// (identical to round-5 source; round-5 bench was an infra failure, audit clean)
//  * Ks/Vs double-buffered; next tile's 8 g2l16 issued BEFORE computing current;
//    counted s_waitcnt vmcnt(8) (never drain mid-loop); raw s_barrier.
//  * Ps pad 80 -> 88 halfwords: stride 44 dw == 12 mod 32 -> conflict-free b128.
//  * longest-first q_tile (work ~ q_tile+1).
// LDS: 2*16K (K) + 2*16K (V) + 11264 (Ps) = 76800 B -> 2 blocks/CU.
__global__ __launch_bounds__(256, 2) void flash(const u16* __restrict__ Qb,
                                                const u16* __restrict__ Kb,
                                                const u16* __restrict__ Vt,
                                                u16* __restrict__ AO) {
  __shared__ __align__(16) u16 Ks[2][64 * 128];   // [buf][row k][chunk'=chunk^(row&15)]
  __shared__ __align__(16) u16 Vs[2][128 * 64];   // [buf][row d][chunk'=chunk^(row&7)]
  __shared__ __align__(16) u16 Ps[4 * 16 * 88];   // per-wave [q=16][k=64 pad->88]

  int tid  = threadIdx.x;
  int lane = tid & 63, w = tid >> 6;
  int ml   = lane & 15, quad = lane >> 4;
  int q_tile = gridDim.x - 1 - blockIdx.x;        // longest-first
  int h = blockIdx.y, b = blockIdx.z;
  int hkv = h >> 2;
  int q0  = q_tile * 64;
  const u16* Qh = Qb + ((size_t)(b * NH + h) * S_LEN) * HD;
  const u16* Kh = Kb + ((size_t)(b * NKV + hkv) * S_LEN) * HD;
  const u16* Vh = Vt + ((size_t)(b * NKV + hkv) * HD) * S_LEN;
  u16* Pw = Ps + w * 16 * 88;

  // hoist Q B-fragments (lane = q row, quad packs k)
  short8 qf[4];
#pragma unroll
  for (int ks = 0; ks < 4; ++ks)
    qf[ks] = *reinterpret_cast<const short8*>(
        Qh + (size_t)(q0 + w * 16 + ml) * HD + ks * 32 + quad * 8);

  short8 ones8;
  {
    u16 one_b = 0x3f80;
#pragma unroll
    for (int j = 0; j < 8; ++j) ones8[j] = (short)one_b;
  }

  f32x4 o[8] = {};
  f32x4 o9 = {};
  const float SC = 0.12751745f;  // (1/sqrt(128)) * log2(e)
  const float BIAS = 18.0f;

  // stage K tile (64x128) and V tile (128x64) for kv-tile IT into buffer D
#define STAGE_KV(IT, D) do { \
    int _kv0 = (IT) * 64; \
    _Pragma("unroll") \
    for (int p = 0; p < 4; ++p) { \
      int slot = w * 256 + p * 64 + lane; \
      int krow = slot >> 4, kch = slot & 15; \
      int ksrc = kch ^ (krow & 15); \
      g2l16(Kh + (size_t)(_kv0 + krow) * HD + ksrc * 8, &Ks[D][(w * 256 + p * 64) * 8]); \
      int vrow = slot >> 3, vch = slot & 7; \
      int vsrc = vch ^ (vrow & 7); \
      g2l16(Vh + (size_t)vrow * S_LEN + _kv0 + vsrc * 8, &Vs[D][(w * 256 + p * 64) * 8]); \
    } \
  } while (0)

  int qg = q0 + w * 16 + ml;
  int ntile = q_tile + 1;

  // prologue: stage tile 0 into buf 0
  STAGE_KV(0, 0);

  for (int it = 0; it < ntile; ++it) {
    int cur = it & 1;
    // issue next tile's loads into the other buffer (its last readers finished
    // in iter it-1 and completed before that iter's trailing barrier)
    if (it + 1 < ntile) {
      STAGE_KV(it + 1, cur ^ 1);
      asm volatile("s_waitcnt vmcnt(8)" ::: "memory");   // current tile resident
    } else {
      asm volatile("s_waitcnt vmcnt(0)" ::: "memory");
    }
    __builtin_amdgcn_s_barrier();
    __builtin_amdgcn_sched_barrier(0);

    int kv0 = it * 64;
    const u16* Kc = &Ks[cur][0];
    const u16* Vc = &Vs[cur][0];

    // S^T tiles: mfma(A=K rows, B=Q rows) -> C[k][q], col=q=ml, row=k=quad*4+r
    f32x4 st[4] = {};
#pragma unroll
    for (int ks = 0; ks < 4; ++ks) {
#pragma unroll
      for (int nt = 0; nt < 4; ++nt) {
        int row = nt * 16 + ml;
        int ch = ((ks << 2) | quad) ^ ml;
        short8 kf = *reinterpret_cast<const short8*>(&Kc[row * 128 + ch * 8]);
        st[nt] = __builtin_amdgcn_mfma_f32_16x16x32_bf16(kf, qf[ks], st[nt], 0, 0, 0);
      }
    }

    bool diag = (it == q_tile);
#pragma unroll
    for (int nt = 0; nt < 4; ++nt) {
      float p0 = exp2f(fmaf(st[nt][0], SC, -BIAS));
      float p1 = exp2f(fmaf(st[nt][1], SC, -BIAS));
      float p2 = exp2f(fmaf(st[nt][2], SC, -BIAS));
      float p3 = exp2f(fmaf(st[nt][3], SC, -BIAS));
      if (diag) {
        int kg = kv0 + nt * 16 + quad * 4;
        if (kg + 0 > qg) p0 = 0.f;
        if (kg + 1 > qg) p1 = 0.f;
        if (kg + 2 > qg) p2 = 0.f;
        if (kg + 3 > qg) p3 = 0.f;
      }
      uint2 pk;
      pk.x = (unsigned)f2b(p0) | ((unsigned)f2b(p1) << 16);
      pk.y = (unsigned)f2b(p2) | ((unsigned)f2b(p3) << 16);
      *reinterpret_cast<uint2*>(&Pw[ml * 88 + nt * 16 + quad * 4]) = pk;
    }
    // wave-private Ps: no barrier needed (lgkmcnt wait auto-inserted)

#pragma unroll
    for (int ks2 = 0; ks2 < 2; ++ks2) {
      short8 pf = *reinterpret_cast<const short8*>(&Pw[ml * 88 + ks2 * 32 + quad * 8]);
#pragma unroll
      for (int dt = 0; dt < 8; ++dt) {
        int row = dt * 16 + ml;
        int ch = ((ks2 << 2) | quad) ^ (ml & 7);
        short8 vf = *reinterpret_cast<const short8*>(&Vc[row * 64 + ch * 8]);
        o[dt] = __builtin_amdgcn_mfma_f32_16x16x32_bf16(pf, vf, o[dt], 0, 0, 0);
      }
      o9 = __builtin_amdgcn_mfma_f32_16x16x32_bf16(pf, ones8, o9, 0, 0, 0);
    }

    // all reads of buf[cur] are complete (consumed by MFMA above); raw barrier
    // so next iteration may stage into buf[cur^1] without draining vmcnt.
    __builtin_amdgcn_s_barrier();
    __builtin_amdgcn_sched_barrier(0);
  }
#undef STAGE_KV

  size_t row_base = (size_t)(b * S_LEN + q0 + w * 16 + quad * 4);
#pragma unroll
  for (int rr = 0; rr < 4; ++rr) {
    float inv_l = 1.0f / o9[rr];
#pragma unroll
    for (int dt = 0; dt < 8; ++dt) {
      int col = h * HD + dt * 16 + ml;
      AO[(row_base + rr) * (size_t)DIM + col] = f2b(o[dt][rr] * inv_l);
    }
  }
}

extern "C" void kernel_launch(void* const* d_in, const int* in_sizes, int n_in,
                              void* d_out, int out_size, void* d_ws, size_t ws_size,
                              hipStream_t stream) {
  const float* x  = (const float*)d_in[0];
  const float* wq = (const float*)d_in[1];
  const float* wk = (const float*)d_in[2];
  const float* wv = (const float*)d_in[3];
  const float* wo = (const float*)d_in[4];
  float* out = (float*)d_out;
  char* ws = (char*)d_ws;

  u16* Wqt = (u16*)(ws + 0);          // [4096][4096], later wo^T
  u16* Wkt = (u16*)(ws + 33554432);   // [1024][4096]
  u16* Wvt = (u16*)(ws + 41943040);   // [1024][4096]
  u16* Xb  = (u16*)(ws + 50331648);   // [4096][4096] bf16, later AO
  u16* Qb  = (u16*)(ws + 83886080);
  u16* Kb  = (u16*)(ws + 117440512);
  u16* Vt  = (u16*)(ws + 125829120);

  transpose_cast<<<dim3(128, 128), dim3(32, 8), 0, stream>>>(wq, Wqt, 4096, 4096);
  transpose_cast<<<dim3(32, 128),  dim3(32, 8), 0, stream>>>(wk, Wkt, 4096, 1024);
  transpose_cast<<<dim3(32, 128),  dim3(32, 8), 0, stream>>>(wv, Wvt, 4096, 1024);
  cast_x<<<16384, 256, 0, stream>>>(x, Xb, 4194304);

  // QKV projection: M=4096, N=6144, K=4096; grid 24x32 = 768 = 3 exact CU rounds
  gemm128<<<dim3(24, 32), 512, 0, stream>>>(Xb, Wqt, Qb, Kb, Vt);

  rope_ip<<<32768, 256, 0, stream>>>(Qb, 8388608);
  rope_ip<<<8192, 256, 0, stream>>>(Kb, 2097152);

  transpose_cast<<<dim3(128, 128), dim3(32, 8), 0, stream>>>(wo, Wqt, 4096, 4096);

  flash<<<dim3(32, 32, 2), 256, 0, stream>>>(Qb, Kb, Vt, Xb);

  // output projection: M=4096, N=4096, K=4096; grid 16x16 = 256 = 1 exact round
  gemm256<<<dim3(16, 16), 512, 0, stream>>>(Xb, Wqt, 4096, out);
}